// Round 1
// baseline (990.673 us; speedup 1.0000x reference)
//
#include <hip/hip_runtime.h>
#include <math.h>

#define NN 50000
#define NEG 0.2f

// ---------------------------------------------------------------- utilities
__global__ void k_zero(int* p, int n){
    int i = blockIdx.x * 256 + threadIdx.x;
    if (i < n) p[i] = 0;
}

// histogram of incoming-edge degree per dst (edges + self loops)
__global__ void k_hist(const int* __restrict__ ei, int E, int* __restrict__ deg){
    int e = blockIdx.x * 256 + threadIdx.x;
    int EP = E + NN;
    if (e < EP){
        int d = (e < E) ? ei[E + e] : (e - E);
        atomicAdd(&deg[d], 1);
    }
}

// exclusive prefix sum over NN degrees -> row_ptr (and cursor copy), single block
__global__ __launch_bounds__(1024) void k_scan(const int* __restrict__ deg,
                                               int* __restrict__ row_ptr,
                                               int* __restrict__ cursor){
    __shared__ int sums[1024];
    int t = threadIdx.x;
    const int chunk = (NN + 1023) / 1024;
    int lo = t * chunk, hi = min(lo + chunk, NN);
    int s = 0;
    for (int i = lo; i < hi; ++i) s += deg[i];
    sums[t] = s;
    __syncthreads();
    for (int off = 1; off < 1024; off <<= 1){
        int v = (t >= off) ? sums[t - off] : 0;
        __syncthreads();
        sums[t] += v;
        __syncthreads();
    }
    int excl = (t == 0) ? 0 : sums[t - 1];
    for (int i = lo; i < hi; ++i){
        int d = deg[i];
        row_ptr[i] = excl;
        cursor[i]  = excl;
        excl += d;
    }
    if (t == 1023) row_ptr[NN] = sums[1023];
}

// bucket edges by dst: ssrc[pos] = src  (order within a segment arbitrary)
__global__ void k_scatter(const int* __restrict__ ei, int E,
                          int* __restrict__ cursor, int* __restrict__ ssrc){
    int e = blockIdx.x * 256 + threadIdx.x;
    int EP = E + NN;
    if (e < EP){
        int s, d;
        if (e < E){ s = ei[e]; d = ei[E + e]; } else { s = e - E; d = s; }
        int pos = atomicAdd(&cursor[d], 1);
        ssrc[pos] = s;
    }
}

// ---------------------------------------------------------------- fp32 GEMM
// C[M,Ncol] = A[M,128] @ B[128,Ncol].  64 x TILEN tile, 256 threads, 4xTN/thread.
template<int TILEN>
__global__ __launch_bounds__(256) void k_gemm(const float* __restrict__ A,
                                              const float* __restrict__ B,
                                              float* __restrict__ C,
                                              int M, int Ncol){
    const int TN = TILEN / 16;
    __shared__ float As[16][64 + 4];
    __shared__ float Bs[16][TILEN + 4];
    int tid = threadIdx.x;
    int tx = tid & 15;     // col group
    int ty = tid >> 4;     // row group
    int rowBase = blockIdx.x * 64;
    int colBase = blockIdx.y * TILEN;

    float acc[4][4];
#pragma unroll
    for (int i = 0; i < 4; ++i)
#pragma unroll
        for (int j = 0; j < 4; ++j) acc[i][j] = 0.f;

    for (int k0 = 0; k0 < 128; k0 += 16){
        { // stage A 64x16 (transposed into LDS), float4 per thread
            int m  = tid >> 2;
            int kk = (tid & 3) << 2;
            int gm_ = rowBase + m;
            float4 v = make_float4(0.f, 0.f, 0.f, 0.f);
            if (gm_ < M) v = *(const float4*)&A[(size_t)gm_ * 128 + k0 + kk];
            As[kk + 0][m] = v.x; As[kk + 1][m] = v.y;
            As[kk + 2][m] = v.z; As[kk + 3][m] = v.w;
        }
        { // stage B 16xTILEN
            const int per_row = TILEN / 4;
            const int nv = 16 * per_row;
            if (tid < nv){
                int kk = tid / per_row;
                int nn = (tid % per_row) * 4;
                float4 v = *(const float4*)&B[(size_t)(k0 + kk) * Ncol + colBase + nn];
                Bs[kk][nn + 0] = v.x; Bs[kk][nn + 1] = v.y;
                Bs[kk][nn + 2] = v.z; Bs[kk][nn + 3] = v.w;
            }
        }
        __syncthreads();
#pragma unroll
        for (int kk = 0; kk < 16; ++kk){
            float a0 = As[kk][ty * 4 + 0];
            float a1 = As[kk][ty * 4 + 1];
            float a2 = As[kk][ty * 4 + 2];
            float a3 = As[kk][ty * 4 + 3];
            float bv[4];
#pragma unroll
            for (int j = 0; j < TN; ++j) bv[j] = Bs[kk][tx * TN + j];
#pragma unroll
            for (int j = 0; j < TN; ++j){
                acc[0][j] += a0 * bv[j];
                acc[1][j] += a1 * bv[j];
                acc[2][j] += a2 * bv[j];
                acc[3][j] += a3 * bv[j];
            }
        }
        __syncthreads();
    }
#pragma unroll
    for (int i = 0; i < 4; ++i){
        int r = rowBase + ty * 4 + i;
        if (r < M){
#pragma unroll
            for (int j = 0; j < TN; ++j)
                C[(size_t)r * Ncol + colBase + tx * TN + j] = acc[i][j];
        }
    }
}

// ------------------------------------------- per-node attention half-logits
// asrc[n,h] = dot(h[n,h,:], a_s[h,:]),  adst likewise.  thread = n*H + h.
__global__ void k_nodealpha(const float* __restrict__ h,
                            const float* __restrict__ a_s,
                            const float* __restrict__ a_d,
                            float* __restrict__ asrc, float* __restrict__ adst,
                            int H, int C){
    int t = blockIdx.x * 256 + threadIdx.x;
    if (t >= NN * H) return;
    int n = t / H, hd = t % H;
    const float* hp = h + (size_t)n * H * C + hd * C;
    float s1 = 0.f, s2 = 0.f;
    for (int c = 0; c < C; c += 4){
        float4 hv = *(const float4*)&hp[c];
        float4 av = *(const float4*)&a_s[hd * C + c];
        float4 dv = *(const float4*)&a_d[hd * C + c];
        s1 += hv.x * av.x + hv.y * av.y + hv.z * av.z + hv.w * av.w;
        s2 += hv.x * dv.x + hv.y * dv.y + hv.z * dv.z + hv.w * dv.w;
    }
    asrc[t] = s1;
    adst[t] = s2;
}

// --------------------------------------------- aggregation, 4 heads x 32 ch
// one wave per dst node.  pass1: online softmax (lane = slot*4 + head),
// butterfly combine.  pass2: lane owns channels {lane, lane+64}.
__global__ __launch_bounds__(256) void k_agg4(
        const float* __restrict__ h, const float* __restrict__ asrc,
        const float* __restrict__ adst, const int* __restrict__ row_ptr,
        const int* __restrict__ ssrc, const float* __restrict__ bias,
        float* __restrict__ outp, float* __restrict__ gm,
        float* __restrict__ gdenom, int writeStats, int applyElu){
    int wave = (blockIdx.x * 256 + threadIdx.x) >> 6;
    int lane = threadIdx.x & 63;
    if (wave >= NN) return;
    int i = wave;
    int lo = row_ptr[i], hi = row_ptr[i + 1];

    // ---- pass 1: max + denom via online softmax
    int hd = lane & 3;
    int s  = lane >> 2;                 // 16 edge slots
    float adv = adst[i * 4 + hd];
    float m = -3.0e38f, sum = 0.f;
    for (int idx = lo + s; idx < hi; idx += 16){
        int j = ssrc[idx];
        float lg = asrc[j * 4 + hd] + adv;
        lg = (lg > 0.f) ? lg : NEG * lg;
        float nm = fmaxf(m, lg);
        sum = sum * __expf(m - nm) + __expf(lg - nm);
        m = nm;
    }
    for (int off = 4; off < 64; off <<= 1){
        float mo = __shfl_xor(m, off);
        float so = __shfl_xor(sum, off);
        float nm = fmaxf(m, mo);
        float pa = (m  == nm) ? sum : sum * __expf(m - nm);
        float pb = (mo == nm) ? so  : so  * __expf(mo - nm);
        m = nm; sum = pa + pb;
    }
    if (writeStats && s == 0){
        gm[i * 4 + hd] = m;
        gdenom[i * 4 + hd] = sum;
    }

    // ---- pass 2: weighted gather-accumulate
    int h0 = lane >> 5;                 // head for channel c0 = lane
    int h1 = 2 + (lane >> 5);           // head for channel c1 = lane + 64
    float m0 = __shfl(m, h0),  d0 = __shfl(sum, h0);
    float m1 = __shfl(m, h1),  d1 = __shfl(sum, h1);
    float r0 = 1.f / d0, r1 = 1.f / d1;
    float ad0v = adst[i * 4 + h0], ad1v = adst[i * 4 + h1];
    float acc0 = 0.f, acc1 = 0.f;
    for (int idx = lo; idx < hi; ++idx){
        int j = ssrc[idx];              // wave-uniform
        float lg0 = asrc[j * 4 + h0] + ad0v; lg0 = (lg0 > 0.f) ? lg0 : NEG * lg0;
        float lg1 = asrc[j * 4 + h1] + ad1v; lg1 = (lg1 > 0.f) ? lg1 : NEG * lg1;
        float w0 = __expf(lg0 - m0) * r0;
        float w1 = __expf(lg1 - m1) * r1;
        acc0 += w0 * h[(size_t)j * 128 + lane];
        acc1 += w1 * h[(size_t)j * 128 + 64 + lane];
    }
    float o0 = acc0 + bias[lane];
    float o1 = acc1 + bias[64 + lane];
    if (applyElu){
        o0 = (o0 > 0.f) ? o0 : (expf(o0) - 1.f);
        o1 = (o1 > 0.f) ? o1 : (expf(o1) - 1.f);
    }
    outp[(size_t)i * 128 + lane]      = o0;
    outp[(size_t)i * 128 + 64 + lane] = o1;
}

// ------------------------------------ alpha0 in ORIGINAL edge order (layer0)
__global__ void k_alpha0(const int* __restrict__ ei, int E,
                         const float* __restrict__ asrc, const float* __restrict__ adst,
                         const float* __restrict__ gm, const float* __restrict__ gdenom,
                         float* __restrict__ out){
    int t = blockIdx.x * 256 + threadIdx.x;
    int EP = E + NN;
    if (t >= EP * 4) return;
    int e = t >> 2, hd = t & 3;
    int s, d;
    if (e < E){ s = ei[e]; d = ei[E + e]; } else { s = e - E; d = s; }
    float lg = asrc[s * 4 + hd] + adst[d * 4 + hd];
    lg = (lg > 0.f) ? lg : NEG * lg;
    out[t] = __expf(lg - gm[d * 4 + hd]) / gdenom[d * 4 + hd];
}

// --------------------------------------------- aggregation, 1 head x 32 ch
__global__ __launch_bounds__(256) void k_agg1(
        const float* __restrict__ h2, const float* __restrict__ asrc,
        const float* __restrict__ adst, const int* __restrict__ row_ptr,
        const int* __restrict__ ssrc, const float* __restrict__ bias,
        float* __restrict__ outp){
    int wave = (blockIdx.x * 256 + threadIdx.x) >> 6;
    int lane = threadIdx.x & 63;
    if (wave >= NN) return;
    int i = wave;
    int lo = row_ptr[i], hi = row_ptr[i + 1];

    float adv = adst[i];
    float m = -3.0e38f, sum = 0.f;
    for (int idx = lo + lane; idx < hi; idx += 64){
        int j = ssrc[idx];
        float lg = asrc[j] + adv;
        lg = (lg > 0.f) ? lg : NEG * lg;
        float nm = fmaxf(m, lg);
        sum = sum * __expf(m - nm) + __expf(lg - nm);
        m = nm;
    }
    for (int off = 1; off < 64; off <<= 1){
        float mo = __shfl_xor(m, off);
        float so = __shfl_xor(sum, off);
        float nm = fmaxf(m, mo);
        float pa = (m  == nm) ? sum : sum * __expf(m - nm);
        float pb = (mo == nm) ? so  : so  * __expf(mo - nm);
        m = nm; sum = pa + pb;
    }
    float r = 1.f / sum;

    int half = lane >> 5;
    int c = lane & 31;
    float acc = 0.f;
    for (int idx = lo + half; idx < hi; idx += 2){
        int j = ssrc[idx];
        float lg = asrc[j] + adv;
        lg = (lg > 0.f) ? lg : NEG * lg;
        float w = __expf(lg - m) * r;
        acc += w * h2[(size_t)j * 32 + c];
    }
    acc += __shfl_xor(acc, 32);
    if (half == 0) outp[(size_t)i * 32 + c] = acc + bias[c];
}

// ---------------------------------------------------------------- launcher
extern "C" void kernel_launch(void* const* d_in, const int* in_sizes, int n_in,
                              void* d_out, int out_size, void* d_ws, size_t ws_size,
                              hipStream_t stream){
    const float* x   = (const float*)d_in[0];
    const int*   ei  = (const int*)  d_in[1];
    const float* W0  = (const float*)d_in[2];
    const float* as0 = (const float*)d_in[3];
    const float* ad0 = (const float*)d_in[4];
    const float* b0  = (const float*)d_in[5];
    const float* W1  = (const float*)d_in[6];
    const float* as1 = (const float*)d_in[7];
    const float* ad1 = (const float*)d_in[8];
    const float* b1  = (const float*)d_in[9];
    const float* W2  = (const float*)d_in[10];
    const float* as2 = (const float*)d_in[11];
    const float* ad2 = (const float*)d_in[12];
    const float* b2  = (const float*)d_in[13];

    const int E  = in_sizes[1] / 2;
    const int EP = E + NN;

    // ---- workspace carve (256B aligned)
    char* w = (char*)d_ws;
    size_t off = 0;
    auto carve = [&](size_t bytes) -> char* {
        char* p = w + off;
        off += (bytes + 255) & ~(size_t)255;
        return p;
    };
    int*   deg     = (int*)  carve(sizeof(int) * NN);
    int*   row_ptr = (int*)  carve(sizeof(int) * (NN + 1));
    int*   cursor  = (int*)  carve(sizeof(int) * NN);
    int*   ssrc    = (int*)  carve(sizeof(int) * (size_t)EP);
    float* hbuf    = (float*)carve(sizeof(float) * (size_t)NN * 128);
    float* postA   = (float*)carve(sizeof(float) * (size_t)NN * 128);
    float* postB   = (float*)carve(sizeof(float) * (size_t)NN * 128);
    float* asrc    = (float*)carve(sizeof(float) * NN * 4);
    float* adst    = (float*)carve(sizeof(float) * NN * 4);
    float* gm      = (float*)carve(sizeof(float) * NN * 4);
    float* gdenom  = (float*)carve(sizeof(float) * NN * 4);

    float* out_alpha = (float*)d_out;                  // [EP, 4]
    float* out_final = (float*)d_out + (size_t)EP * 4; // [NN, 32]

    const int edgeBlocks = (EP + 255) / 256;
    const int waveBlocks = (NN + 3) / 4;               // 1 wave per node, 4 waves/block
    const dim3 gemmGrid128((NN + 63) / 64, 2);
    const dim3 gemmGrid32((NN + 63) / 64, 1);

    // ---- CSR build (topology shared by all 3 layers)
    k_zero   <<<(NN + 255) / 256, 256, 0, stream>>>(deg, NN);
    k_hist   <<<edgeBlocks, 256, 0, stream>>>(ei, E, deg);
    k_scan   <<<1, 1024, 0, stream>>>(deg, row_ptr, cursor);
    k_scatter<<<edgeBlocks, 256, 0, stream>>>(ei, E, cursor, ssrc);

    // ---- layer 0
    k_gemm<64><<<gemmGrid128, 256, 0, stream>>>(x, W0, hbuf, NN, 128);
    k_nodealpha<<<(NN * 4 + 255) / 256, 256, 0, stream>>>(hbuf, as0, ad0, asrc, adst, 4, 32);
    k_agg4<<<waveBlocks, 256, 0, stream>>>(hbuf, asrc, adst, row_ptr, ssrc, b0,
                                           postA, gm, gdenom, 1, 1);
    k_alpha0<<<((size_t)EP * 4 + 255) / 256, 256, 0, stream>>>(ei, E, asrc, adst,
                                                               gm, gdenom, out_alpha);

    // ---- layer 1
    k_gemm<64><<<gemmGrid128, 256, 0, stream>>>(postA, W1, hbuf, NN, 128);
    k_nodealpha<<<(NN * 4 + 255) / 256, 256, 0, stream>>>(hbuf, as1, ad1, asrc, adst, 4, 32);
    k_agg4<<<waveBlocks, 256, 0, stream>>>(hbuf, asrc, adst, row_ptr, ssrc, b1,
                                           postB, gm, gdenom, 0, 1);

    // ---- layer 2 (1 head, 32 out, no concat/ELU)
    k_gemm<32><<<gemmGrid32, 256, 0, stream>>>(postB, W2, hbuf, NN, 32);
    k_nodealpha<<<(NN + 255) / 256, 256, 0, stream>>>(hbuf, as2, ad2, asrc, adst, 1, 32);
    k_agg1<<<waveBlocks, 256, 0, stream>>>(hbuf, asrc, adst, row_ptr, ssrc, b2, out_final);
}

// Round 2
// 783.032 us; speedup vs baseline: 1.2652x; 1.2652x over previous
//
#include <hip/hip_runtime.h>
#include <math.h>

#define NN 50000
#define NEG 0.2f

__device__ __forceinline__ unsigned short f2bf(float f){
    unsigned u = __float_as_uint(f);
    u += 0x7fffu + ((u >> 16) & 1u);   // round-to-nearest-even
    return (unsigned short)(u >> 16);
}

// ---------------------------------------------------------------- utilities
__global__ void k_zero(int* p, int n){
    int i = blockIdx.x * 256 + threadIdx.x;
    if (i < n) p[i] = 0;
}

__global__ void k_hist(const int* __restrict__ ei, int E, int* __restrict__ deg){
    int e = blockIdx.x * 256 + threadIdx.x;
    int EP = E + NN;
    if (e < EP){
        int d = (e < E) ? ei[E + e] : (e - E);
        atomicAdd(&deg[d], 1);
    }
}

__global__ __launch_bounds__(1024) void k_scan(const int* __restrict__ deg,
                                               int* __restrict__ row_ptr,
                                               int* __restrict__ cursor){
    __shared__ int sums[1024];
    int t = threadIdx.x;
    const int chunk = (NN + 1023) / 1024;
    int lo = t * chunk, hi = min(lo + chunk, NN);
    int s = 0;
    for (int i = lo; i < hi; ++i) s += deg[i];
    sums[t] = s;
    __syncthreads();
    for (int off = 1; off < 1024; off <<= 1){
        int v = (t >= off) ? sums[t - off] : 0;
        __syncthreads();
        sums[t] += v;
        __syncthreads();
    }
    int excl = (t == 0) ? 0 : sums[t - 1];
    for (int i = lo; i < hi; ++i){
        int d = deg[i];
        row_ptr[i] = excl;
        cursor[i]  = excl;
        excl += d;
    }
    if (t == 1023) row_ptr[NN] = sums[1023];
}

__global__ void k_scatter(const int* __restrict__ ei, int E,
                          int* __restrict__ cursor, int* __restrict__ ssrc){
    int e = blockIdx.x * 256 + threadIdx.x;
    int EP = E + NN;
    if (e < EP){
        int s, d;
        if (e < E){ s = ei[e]; d = ei[E + e]; } else { s = e - E; d = s; }
        int pos = atomicAdd(&cursor[d], 1);
        ssrc[pos] = s;
    }
}

// ---------------------------------------------------------------- fp32 GEMM
// C[M,Ncol] = A[M,128] @ B[128,Ncol].  64 x TILEN tile, 256 threads.
// Optionally also writes a packed-bf16 copy (for the gather kernels).
template<int TILEN>
__global__ __launch_bounds__(256) void k_gemm(const float* __restrict__ A,
                                              const float* __restrict__ B,
                                              float* __restrict__ C,
                                              unsigned short* __restrict__ Cbf,
                                              int M, int Ncol){
    const int TN = TILEN / 16;
    __shared__ __align__(16) float As[16][68];
    __shared__ __align__(16) float Bs[16][TILEN + 4];
    int tid = threadIdx.x;
    int tx = tid & 15;
    int ty = tid >> 4;
    int rowBase = blockIdx.x * 64;
    int colBase = blockIdx.y * TILEN;

    float acc[4][TN];
#pragma unroll
    for (int i = 0; i < 4; ++i)
#pragma unroll
        for (int j = 0; j < TN; ++j) acc[i][j] = 0.f;

    for (int k0 = 0; k0 < 128; k0 += 16){
        {
            int m  = tid >> 2;
            int kk = (tid & 3) << 2;
            int gm_ = rowBase + m;
            float4 v = make_float4(0.f, 0.f, 0.f, 0.f);
            if (gm_ < M) v = *(const float4*)&A[(size_t)gm_ * 128 + k0 + kk];
            As[kk + 0][m] = v.x; As[kk + 1][m] = v.y;
            As[kk + 2][m] = v.z; As[kk + 3][m] = v.w;
        }
        {
            const int per_row = TILEN / 4;
            const int nv = 16 * per_row;
            if (tid < nv){
                int kk = tid / per_row;
                int nn = (tid % per_row) * 4;
                float4 v = *(const float4*)&B[(size_t)(k0 + kk) * Ncol + colBase + nn];
                Bs[kk][nn + 0] = v.x; Bs[kk][nn + 1] = v.y;
                Bs[kk][nn + 2] = v.z; Bs[kk][nn + 3] = v.w;
            }
        }
        __syncthreads();
#pragma unroll
        for (int kk = 0; kk < 16; ++kk){
            float4 av = *(const float4*)&As[kk][ty * 4];   // b128
            float a[4] = {av.x, av.y, av.z, av.w};
            float bv[TN];
            if (TN == 4){
                float4 b4 = *(const float4*)&Bs[kk][tx * 4];  // b128
                bv[0] = b4.x; bv[1] = b4.y; bv[2] = b4.z; bv[3] = b4.w;
            } else {
                float2 b2 = *(const float2*)&Bs[kk][tx * 2];
                bv[0] = b2.x; bv[1] = b2.y;
            }
#pragma unroll
            for (int i = 0; i < 4; ++i)
#pragma unroll
                for (int j = 0; j < TN; ++j)
                    acc[i][j] += a[i] * bv[j];
        }
        __syncthreads();
    }
#pragma unroll
    for (int i = 0; i < 4; ++i){
        int r = rowBase + ty * 4 + i;
        if (r < M){
            if (TN == 4){
                float4 v = make_float4(acc[i][0], acc[i][1], acc[i][2], acc[i][3]);
                *(float4*)&C[(size_t)r * Ncol + colBase + tx * 4] = v;
                if (Cbf){
                    unsigned p0 = (unsigned)f2bf(acc[i][0]) | ((unsigned)f2bf(acc[i][1]) << 16);
                    unsigned p1 = (unsigned)f2bf(acc[i][2]) | ((unsigned)f2bf(acc[i][3]) << 16);
                    *(uint2*)&Cbf[(size_t)r * Ncol + colBase + tx * 4] = make_uint2(p0, p1);
                }
            } else {
                *(float2*)&C[(size_t)r * Ncol + colBase + tx * 2] =
                    make_float2(acc[i][0], acc[i][1]);
            }
        }
    }
}

// ------------------------------------------- per-node attention half-logits
__global__ void k_nodealpha(const float* __restrict__ h,
                            const float* __restrict__ a_s,
                            const float* __restrict__ a_d,
                            float* __restrict__ asrc, float* __restrict__ adst,
                            int H, int C){
    int t = blockIdx.x * 256 + threadIdx.x;
    if (t >= NN * H) return;
    int n = t / H, hd = t % H;
    const float* hp = h + (size_t)n * H * C + hd * C;
    float s1 = 0.f, s2 = 0.f;
    for (int c = 0; c < C; c += 4){
        float4 hv = *(const float4*)&hp[c];
        float4 av = *(const float4*)&a_s[hd * C + c];
        float4 dv = *(const float4*)&a_d[hd * C + c];
        s1 += hv.x * av.x + hv.y * av.y + hv.z * av.z + hv.w * av.w;
        s2 += hv.x * dv.x + hv.y * dv.y + hv.z * dv.z + hv.w * dv.w;
    }
    asrc[t] = s1;
    adst[t] = s2;
}

// --------------------------------------------- aggregation, 4 heads x 32 ch
// one wave per dst node. pass1: online softmax (lane = slot*4 + head).
// pass2: lane owns channels {2*lane, 2*lane+1} (head = lane>>4), bf16 gather.
__global__ __launch_bounds__(256) void k_agg4(
        const unsigned* __restrict__ hb,          // packed bf16x2 rows [NN][64]
        const float* __restrict__ asrc, const float* __restrict__ adst,
        const int* __restrict__ row_ptr, const int* __restrict__ ssrc,
        const float* __restrict__ bias, float* __restrict__ outp,
        float* __restrict__ gm, float* __restrict__ gdenom, int writeStats){
    int wave = (blockIdx.x * 256 + threadIdx.x) >> 6;
    int lane = threadIdx.x & 63;
    if (wave >= NN) return;
    int i = wave;
    int lo = row_ptr[i], hi = row_ptr[i + 1];

    // ---- pass 1: max + denom
    int hd = lane & 3;
    int s  = lane >> 2;
    float adv1 = adst[i * 4 + hd];
    float m = -3.0e38f, sum = 0.f;
    for (int idx = lo + s; idx < hi; idx += 16){
        int j = ssrc[idx];
        float lg = asrc[j * 4 + hd] + adv1;
        lg = (lg > 0.f) ? lg : NEG * lg;
        float nm = fmaxf(m, lg);
        sum = sum * __expf(m - nm) + __expf(lg - nm);
        m = nm;
    }
    for (int off = 4; off < 64; off <<= 1){
        float mo = __shfl_xor(m, off);
        float so = __shfl_xor(sum, off);
        float nm = fmaxf(m, mo);
        float pa = (m  == nm) ? sum : sum * __expf(m - nm);
        float pb = (mo == nm) ? so  : so  * __expf(mo - nm);
        m = nm; sum = pa + pb;
    }
    if (writeStats && s == 0){
        gm[i * 4 + hd] = m;
        gdenom[i * 4 + hd] = sum;
    }

    // ---- pass 2: weighted bf16 gather, 4x unrolled for MLP
    int myh = lane >> 4;
    float mh = __shfl(m, myh);
    float rh = 1.f / __shfl(sum, myh);
    float adv = adst[i * 4 + myh];
    float acc0 = 0.f, acc1 = 0.f;
    int idx = lo;
#define GAT_DO(gx, ax) { float lg = (ax) + adv; lg = (lg > 0.f) ? lg : NEG * lg;  \
        float w = __expf(lg - mh) * rh;                                           \
        acc0 += w * __uint_as_float((gx) << 16);                                  \
        acc1 += w * __uint_as_float((gx) & 0xffff0000u); }
    for (; idx + 4 <= hi; idx += 4){
        int j0 = ssrc[idx], j1 = ssrc[idx + 1], j2 = ssrc[idx + 2], j3 = ssrc[idx + 3];
        unsigned g0 = hb[(size_t)j0 * 64 + lane];
        unsigned g1 = hb[(size_t)j1 * 64 + lane];
        unsigned g2 = hb[(size_t)j2 * 64 + lane];
        unsigned g3 = hb[(size_t)j3 * 64 + lane];
        float a0 = asrc[j0 * 4 + myh], a1 = asrc[j1 * 4 + myh];
        float a2 = asrc[j2 * 4 + myh], a3 = asrc[j3 * 4 + myh];
        GAT_DO(g0, a0) GAT_DO(g1, a1) GAT_DO(g2, a2) GAT_DO(g3, a3)
    }
    for (; idx < hi; ++idx){
        int j = ssrc[idx];
        unsigned g = hb[(size_t)j * 64 + lane];
        float a = asrc[j * 4 + myh];
        GAT_DO(g, a)
    }
#undef GAT_DO
    int c0 = 2 * lane;
    float o0 = acc0 + bias[c0];
    float o1 = acc1 + bias[c0 + 1];
    o0 = (o0 > 0.f) ? o0 : (__expf(o0) - 1.f);   // ELU (both agg4 layers apply it)
    o1 = (o1 > 0.f) ? o1 : (__expf(o1) - 1.f);
    *(float2*)&outp[(size_t)i * 128 + c0] = make_float2(o0, o1);
}

// ------------------------------------ alpha0 in ORIGINAL edge order (layer0)
// one thread per edge, float4 loads/stores (all 4 heads at once)
__global__ void k_alpha0(const int* __restrict__ ei, int E,
                         const float4* __restrict__ asrc4, const float4* __restrict__ adst4,
                         const float4* __restrict__ gm4, const float4* __restrict__ gd4,
                         float4* __restrict__ out){
    int e = blockIdx.x * 256 + threadIdx.x;
    int EP = E + NN;
    if (e >= EP) return;
    int s, d;
    if (e < E){ s = ei[e]; d = ei[E + e]; } else { s = e - E; d = s; }
    float4 as = asrc4[s], ad = adst4[d], mm = gm4[d], dn = gd4[d];
    float4 r;
    float lg;
    lg = as.x + ad.x; lg = (lg > 0.f) ? lg : NEG * lg; r.x = __expf(lg - mm.x) / dn.x;
    lg = as.y + ad.y; lg = (lg > 0.f) ? lg : NEG * lg; r.y = __expf(lg - mm.y) / dn.y;
    lg = as.z + ad.z; lg = (lg > 0.f) ? lg : NEG * lg; r.z = __expf(lg - mm.z) / dn.z;
    lg = as.w + ad.w; lg = (lg > 0.f) ? lg : NEG * lg; r.w = __expf(lg - mm.w) / dn.w;
    out[e] = r;
}

// --------------------------------------------- aggregation, 1 head x 32 ch
__global__ __launch_bounds__(256) void k_agg1(
        const float* __restrict__ h2, const float* __restrict__ asrc,
        const float* __restrict__ adst, const int* __restrict__ row_ptr,
        const int* __restrict__ ssrc, const float* __restrict__ bias,
        float* __restrict__ outp){
    int wave = (blockIdx.x * 256 + threadIdx.x) >> 6;
    int lane = threadIdx.x & 63;
    if (wave >= NN) return;
    int i = wave;
    int lo = row_ptr[i], hi = row_ptr[i + 1];

    float adv = adst[i];
    float m = -3.0e38f, sum = 0.f;
    for (int idx = lo + lane; idx < hi; idx += 64){
        int j = ssrc[idx];
        float lg = asrc[j] + adv;
        lg = (lg > 0.f) ? lg : NEG * lg;
        float nm = fmaxf(m, lg);
        sum = sum * __expf(m - nm) + __expf(lg - nm);
        m = nm;
    }
    for (int off = 1; off < 64; off <<= 1){
        float mo = __shfl_xor(m, off);
        float so = __shfl_xor(sum, off);
        float nm = fmaxf(m, mo);
        float pa = (m  == nm) ? sum : sum * __expf(m - nm);
        float pb = (mo == nm) ? so  : so  * __expf(mo - nm);
        m = nm; sum = pa + pb;
    }
    float r = 1.f / sum;

    int half = lane >> 5;
    int c = lane & 31;
    float acc = 0.f;
    int idx = lo + half;
    for (; idx + 2 < hi; idx += 4){        // 2x unroll (stride 2 per half)
        int j0 = ssrc[idx], j1 = ssrc[idx + 2];
        float v0 = h2[(size_t)j0 * 32 + c];
        float v1 = h2[(size_t)j1 * 32 + c];
        float l0 = asrc[j0] + adv; l0 = (l0 > 0.f) ? l0 : NEG * l0;
        float l1 = asrc[j1] + adv; l1 = (l1 > 0.f) ? l1 : NEG * l1;
        acc += __expf(l0 - m) * r * v0;
        acc += __expf(l1 - m) * r * v1;
    }
    for (; idx < hi; idx += 2){
        int j = ssrc[idx];
        float lg = asrc[j] + adv;
        lg = (lg > 0.f) ? lg : NEG * lg;
        acc += __expf(lg - m) * r * h2[(size_t)j * 32 + c];
    }
    acc += __shfl_xor(acc, 32);
    if (half == 0) outp[(size_t)i * 32 + c] = acc + bias[c];
}

// ---------------------------------------------------------------- launcher
extern "C" void kernel_launch(void* const* d_in, const int* in_sizes, int n_in,
                              void* d_out, int out_size, void* d_ws, size_t ws_size,
                              hipStream_t stream){
    const float* x   = (const float*)d_in[0];
    const int*   ei  = (const int*)  d_in[1];
    const float* W0  = (const float*)d_in[2];
    const float* as0 = (const float*)d_in[3];
    const float* ad0 = (const float*)d_in[4];
    const float* b0  = (const float*)d_in[5];
    const float* W1  = (const float*)d_in[6];
    const float* as1 = (const float*)d_in[7];
    const float* ad1 = (const float*)d_in[8];
    const float* b1  = (const float*)d_in[9];
    const float* W2  = (const float*)d_in[10];
    const float* as2 = (const float*)d_in[11];
    const float* ad2 = (const float*)d_in[12];
    const float* b2  = (const float*)d_in[13];

    const int E  = in_sizes[1] / 2;
    const int EP = E + NN;

    char* w = (char*)d_ws;
    size_t off = 0;
    auto carve = [&](size_t bytes) -> char* {
        char* p = w + off;
        off += (bytes + 255) & ~(size_t)255;
        return p;
    };
    int*            deg     = (int*)           carve(sizeof(int) * NN);
    int*            row_ptr = (int*)           carve(sizeof(int) * (NN + 1));
    int*            cursor  = (int*)           carve(sizeof(int) * NN);
    int*            ssrc    = (int*)           carve(sizeof(int) * (size_t)EP);
    float*          hbuf    = (float*)         carve(sizeof(float) * (size_t)NN * 128);
    unsigned short* hb16    = (unsigned short*)carve(sizeof(short) * (size_t)NN * 128);
    float*          post    = (float*)         carve(sizeof(float) * (size_t)NN * 128);
    float*          asrc    = (float*)         carve(sizeof(float) * NN * 4);
    float*          adst    = (float*)         carve(sizeof(float) * NN * 4);
    float*          gm      = (float*)         carve(sizeof(float) * NN * 4);
    float*          gdenom  = (float*)         carve(sizeof(float) * NN * 4);

    float* out_alpha = (float*)d_out;                  // [EP, 4]
    float* out_final = (float*)d_out + (size_t)EP * 4; // [NN, 32]

    const int edgeBlocks = (EP + 255) / 256;
    const int waveBlocks = (NN + 3) / 4;
    const dim3 gemmGrid128((NN + 63) / 64, 2);
    const dim3 gemmGrid32((NN + 63) / 64, 1);

    // ---- CSR build (topology shared by all 3 layers)
    k_zero   <<<(NN + 255) / 256, 256, 0, stream>>>(deg, NN);
    k_hist   <<<edgeBlocks, 256, 0, stream>>>(ei, E, deg);
    k_scan   <<<1, 1024, 0, stream>>>(deg, row_ptr, cursor);
    k_scatter<<<edgeBlocks, 256, 0, stream>>>(ei, E, cursor, ssrc);

    // ---- layer 0
    k_gemm<64><<<gemmGrid128, 256, 0, stream>>>(x, W0, hbuf, hb16, NN, 128);
    k_nodealpha<<<(NN * 4 + 255) / 256, 256, 0, stream>>>(hbuf, as0, ad0, asrc, adst, 4, 32);
    k_agg4<<<waveBlocks, 256, 0, stream>>>((const unsigned*)hb16, asrc, adst, row_ptr,
                                           ssrc, b0, post, gm, gdenom, 1);
    k_alpha0<<<edgeBlocks, 256, 0, stream>>>(ei, E, (const float4*)asrc, (const float4*)adst,
                                             (const float4*)gm, (const float4*)gdenom,
                                             (float4*)out_alpha);

    // ---- layer 1
    k_gemm<64><<<gemmGrid128, 256, 0, stream>>>(post, W1, hbuf, hb16, NN, 128);
    k_nodealpha<<<(NN * 4 + 255) / 256, 256, 0, stream>>>(hbuf, as1, ad1, asrc, adst, 4, 32);
    k_agg4<<<waveBlocks, 256, 0, stream>>>((const unsigned*)hb16, asrc, adst, row_ptr,
                                           ssrc, b1, post, gm, gdenom, 0);

    // ---- layer 2 (1 head, 32 out, no concat/ELU)
    k_gemm<32><<<gemmGrid32, 256, 0, stream>>>(post, W2, hbuf, nullptr, NN, 32);
    k_nodealpha<<<(NN + 255) / 256, 256, 0, stream>>>(hbuf, as2, ad2, asrc, adst, 1, 32);
    k_agg1<<<waveBlocks, 256, 0, stream>>>(hbuf, asrc, adst, row_ptr, ssrc, b2, out_final);
}

// Round 3
// 499.640 us; speedup vs baseline: 1.9828x; 1.5672x over previous
//
#include <hip/hip_runtime.h>
#include <math.h>

#define NN 50000
#define NEG 0.2f
#define TILE 4096      // edges per binning block
#define BCAP 16384     // per-bucket tmp capacity (mean 8.7k, sd 93 -> safe)

__device__ __forceinline__ unsigned short f2bf(float f){
    unsigned u = __float_as_uint(f);
    u += 0x7fffu + ((u >> 16) & 1u);   // round-to-nearest-even
    return (unsigned short)(u >> 16);
}

// exclusive scan of 256 values across a 256-thread block (Hillis-Steele in LDS)
__device__ __forceinline__ int excl_scan_256(int v, int* buf, int tid){
    buf[tid] = v;
    __syncthreads();
#pragma unroll
    for (int off = 1; off < 256; off <<= 1){
        int t = (tid >= off) ? buf[tid - off] : 0;
        __syncthreads();
        buf[tid] += t;
        __syncthreads();
    }
    return buf[tid] - v;
}

// ---------------------------------------------------------------- utilities
__global__ void k_zero(int* p, int n){
    int i = blockIdx.x * 256 + threadIdx.x;
    if (i < n) p[i] = 0;
}

// ---------------------- CSR build pass 1: coarse binning (bucket = dst>>8)
// LDS-staged so global writes are bucket-contiguous runs (coalesced lines).
__global__ __launch_bounds__(256) void k_binning(const int* __restrict__ ei, int E,
        int* __restrict__ bucketCount, unsigned* __restrict__ tmp){
    __shared__ unsigned stage[TILE];
    __shared__ int hist[256], sbuf[256], exs[256], cur[256], gbase[256];
    int tid = threadIdx.x;
    int EP = E + NN;
    int tileBase = blockIdx.x * TILE;
    int cnt = min(TILE, EP - tileBase);

    hist[tid] = 0;
    __syncthreads();

    unsigned packed[16];
#pragma unroll
    for (int k = 0; k < 16; ++k){
        int e = tileBase + tid + (k << 8);
        unsigned p = 0xffffffffu;
        if (e < EP){
            int s, d;
            if (e < E){ s = ei[e]; d = ei[E + e]; } else { s = e - E; d = s; }
            p = ((unsigned)d << 16) | (unsigned)s;   // d,s < 65536
            atomicAdd(&hist[d >> 8], 1);
        }
        packed[k] = p;
    }
    __syncthreads();
    int h = hist[tid];
    int ex = excl_scan_256(h, sbuf, tid);
    exs[tid] = ex;
    cur[tid] = ex;
    __syncthreads();
#pragma unroll
    for (int k = 0; k < 16; ++k){
        unsigned p = packed[k];
        if (p != 0xffffffffu){
            int b = p >> 24;                     // dst >> 8
            int pos = atomicAdd(&cur[b], 1);
            stage[pos] = p;
        }
    }
    gbase[tid] = atomicAdd(&bucketCount[tid], h);  // 256 global atomics / block
    __syncthreads();
    for (int i = tid; i < cnt; i += 256){
        unsigned p = stage[i];
        int b = p >> 24;
        tmp[(b << 14) + gbase[b] + (i - exs[b])] = p;
    }
}

// ---------------------- CSR build pass 2: per-bucket fine CSR, all LDS-local
// one block per bucket; row_ptr written coalesced; ssrc scatter lands in a
// ~34KB L2-hot window per block.
__global__ __launch_bounds__(256) void k_bucket_csr(int EP,
        const int* __restrict__ bucketCount, const unsigned* __restrict__ tmp,
        int* __restrict__ row_ptr, unsigned short* __restrict__ ssrc){
    __shared__ int sbuf[256], deg[256], cur[256];
    __shared__ int baseSh, nSh;
    int b = blockIdx.x;
    int tid = threadIdx.x;
    int c = bucketCount[tid];
    int exb = excl_scan_256(c, sbuf, tid);
    if (tid == b){ baseSh = exb; nSh = c; }
    deg[tid] = 0;
    __syncthreads();
    int base = baseSh, n = nSh;
    const unsigned* tb = tmp + ((size_t)b << 14);
    for (int i = tid; i < n; i += 256)
        atomicAdd(&deg[(tb[i] >> 16) & 255], 1);
    __syncthreads();
    int d = deg[tid];
    int dx = excl_scan_256(d, sbuf, tid);
    cur[tid] = dx;
    int dst = (b << 8) + tid;
    if (dst < NN) row_ptr[dst] = base + dx;
    if (b == 0 && tid == 0) row_ptr[NN] = EP;
    __syncthreads();
    for (int i = tid; i < n; i += 256){
        unsigned p = tb[i];
        int pos = atomicAdd(&cur[(p >> 16) & 255], 1);
        ssrc[base + pos] = (unsigned short)(p & 0xffffu);
    }
}

// ---------------------------------------------------------------- fp32 GEMM
template<int TILEN>
__global__ __launch_bounds__(256) void k_gemm(const float* __restrict__ A,
                                              const float* __restrict__ B,
                                              float* __restrict__ C,
                                              unsigned short* __restrict__ Cbf,
                                              int M, int Ncol){
    const int TN = TILEN / 16;
    __shared__ __align__(16) float As[16][68];
    __shared__ __align__(16) float Bs[16][TILEN + 4];
    int tid = threadIdx.x;
    int tx = tid & 15;
    int ty = tid >> 4;
    int rowBase = blockIdx.x * 64;
    int colBase = blockIdx.y * TILEN;

    float acc[4][TN];
#pragma unroll
    for (int i = 0; i < 4; ++i)
#pragma unroll
        for (int j = 0; j < TN; ++j) acc[i][j] = 0.f;

    for (int k0 = 0; k0 < 128; k0 += 16){
        {
            int m  = tid >> 2;
            int kk = (tid & 3) << 2;
            int gm_ = rowBase + m;
            float4 v = make_float4(0.f, 0.f, 0.f, 0.f);
            if (gm_ < M) v = *(const float4*)&A[(size_t)gm_ * 128 + k0 + kk];
            As[kk + 0][m] = v.x; As[kk + 1][m] = v.y;
            As[kk + 2][m] = v.z; As[kk + 3][m] = v.w;
        }
        {
            const int per_row = TILEN / 4;
            const int nv = 16 * per_row;
            if (tid < nv){
                int kk = tid / per_row;
                int nn = (tid % per_row) * 4;
                float4 v = *(const float4*)&B[(size_t)(k0 + kk) * Ncol + colBase + nn];
                Bs[kk][nn + 0] = v.x; Bs[kk][nn + 1] = v.y;
                Bs[kk][nn + 2] = v.z; Bs[kk][nn + 3] = v.w;
            }
        }
        __syncthreads();
#pragma unroll
        for (int kk = 0; kk < 16; ++kk){
            float4 av = *(const float4*)&As[kk][ty * 4];
            float a[4] = {av.x, av.y, av.z, av.w};
            float bv[TN];
            if (TN == 4){
                float4 b4 = *(const float4*)&Bs[kk][tx * 4];
                bv[0] = b4.x; bv[1] = b4.y; bv[2] = b4.z; bv[3] = b4.w;
            } else {
                float2 b2 = *(const float2*)&Bs[kk][tx * 2];
                bv[0] = b2.x; bv[1] = b2.y;
            }
#pragma unroll
            for (int i = 0; i < 4; ++i)
#pragma unroll
                for (int j = 0; j < TN; ++j)
                    acc[i][j] += a[i] * bv[j];
        }
        __syncthreads();
    }
#pragma unroll
    for (int i = 0; i < 4; ++i){
        int r = rowBase + ty * 4 + i;
        if (r < M){
            if (TN == 4){
                float4 v = make_float4(acc[i][0], acc[i][1], acc[i][2], acc[i][3]);
                *(float4*)&C[(size_t)r * Ncol + colBase + tx * 4] = v;
                if (Cbf){
                    unsigned p0 = (unsigned)f2bf(acc[i][0]) | ((unsigned)f2bf(acc[i][1]) << 16);
                    unsigned p1 = (unsigned)f2bf(acc[i][2]) | ((unsigned)f2bf(acc[i][3]) << 16);
                    *(uint2*)&Cbf[(size_t)r * Ncol + colBase + tx * 4] = make_uint2(p0, p1);
                }
            } else {
                *(float2*)&C[(size_t)r * Ncol + colBase + tx * 2] =
                    make_float2(acc[i][0], acc[i][1]);
            }
        }
    }
}

// ------------------------------------------- per-node attention half-logits
__global__ void k_nodealpha(const float* __restrict__ h,
                            const float* __restrict__ a_s,
                            const float* __restrict__ a_d,
                            float* __restrict__ asrc, float* __restrict__ adst,
                            int H, int C){
    int t = blockIdx.x * 256 + threadIdx.x;
    if (t >= NN * H) return;
    int n = t / H, hd = t % H;
    const float* hp = h + (size_t)n * H * C + hd * C;
    float s1 = 0.f, s2 = 0.f;
    for (int c = 0; c < C; c += 4){
        float4 hv = *(const float4*)&hp[c];
        float4 av = *(const float4*)&a_s[hd * C + c];
        float4 dv = *(const float4*)&a_d[hd * C + c];
        s1 += hv.x * av.x + hv.y * av.y + hv.z * av.z + hv.w * av.w;
        s2 += hv.x * dv.x + hv.y * dv.y + hv.z * dv.z + hv.w * dv.w;
    }
    asrc[t] = s1;
    adst[t] = s2;
}

// --------------------------------------------- aggregation, 4 heads x 32 ch
__global__ __launch_bounds__(256) void k_agg4(
        const unsigned* __restrict__ hb,          // packed bf16x2 rows [NN][64]
        const float* __restrict__ asrc, const float* __restrict__ adst,
        const int* __restrict__ row_ptr, const unsigned short* __restrict__ ssrc,
        const float* __restrict__ bias, float* __restrict__ outp,
        float* __restrict__ gm, float* __restrict__ gdenom, int writeStats){
    int wave = (blockIdx.x * 256 + threadIdx.x) >> 6;
    int lane = threadIdx.x & 63;
    if (wave >= NN) return;
    int i = wave;
    int lo = row_ptr[i], hi = row_ptr[i + 1];

    // ---- pass 1: max + denom (lane = slot*4 + head)
    int hd = lane & 3;
    int s  = lane >> 2;
    float adv1 = adst[i * 4 + hd];
    float m = -3.0e38f, sum = 0.f;
    for (int idx = lo + s; idx < hi; idx += 16){
        int j = (int)ssrc[idx];
        float lg = asrc[j * 4 + hd] + adv1;
        lg = (lg > 0.f) ? lg : NEG * lg;
        float nm = fmaxf(m, lg);
        sum = sum * __expf(m - nm) + __expf(lg - nm);
        m = nm;
    }
    for (int off = 4; off < 64; off <<= 1){
        float mo = __shfl_xor(m, off);
        float so = __shfl_xor(sum, off);
        float nm = fmaxf(m, mo);
        float pa = (m  == nm) ? sum : sum * __expf(m - nm);
        float pb = (mo == nm) ? so  : so  * __expf(mo - nm);
        m = nm; sum = pa + pb;
    }
    if (writeStats && s == 0){
        gm[i * 4 + hd] = m;
        gdenom[i * 4 + hd] = sum;
    }

    // ---- pass 2: weighted bf16 gather, 4x unrolled (lane owns ch 2l,2l+1)
    int myh = lane >> 4;
    float mh = __shfl(m, myh);
    float rh = 1.f / __shfl(sum, myh);
    float adv = adst[i * 4 + myh];
    float acc0 = 0.f, acc1 = 0.f;
    int idx = lo;
#define GAT_DO(gx, ax) { float lg = (ax) + adv; lg = (lg > 0.f) ? lg : NEG * lg;  \
        float w = __expf(lg - mh) * rh;                                           \
        acc0 += w * __uint_as_float((gx) << 16);                                  \
        acc1 += w * __uint_as_float((gx) & 0xffff0000u); }
    for (; idx + 4 <= hi; idx += 4){
        int j0 = (int)ssrc[idx],     j1 = (int)ssrc[idx + 1];
        int j2 = (int)ssrc[idx + 2], j3 = (int)ssrc[idx + 3];
        unsigned g0 = hb[(size_t)j0 * 64 + lane];
        unsigned g1 = hb[(size_t)j1 * 64 + lane];
        unsigned g2 = hb[(size_t)j2 * 64 + lane];
        unsigned g3 = hb[(size_t)j3 * 64 + lane];
        float a0 = asrc[j0 * 4 + myh], a1 = asrc[j1 * 4 + myh];
        float a2 = asrc[j2 * 4 + myh], a3 = asrc[j3 * 4 + myh];
        GAT_DO(g0, a0) GAT_DO(g1, a1) GAT_DO(g2, a2) GAT_DO(g3, a3)
    }
    for (; idx < hi; ++idx){
        int j = (int)ssrc[idx];
        unsigned g = hb[(size_t)j * 64 + lane];
        float a = asrc[j * 4 + myh];
        GAT_DO(g, a)
    }
#undef GAT_DO
    int c0 = 2 * lane;
    float o0 = acc0 + bias[c0];
    float o1 = acc1 + bias[c0 + 1];
    o0 = (o0 > 0.f) ? o0 : (__expf(o0) - 1.f);   // ELU
    o1 = (o1 > 0.f) ? o1 : (__expf(o1) - 1.f);
    *(float2*)&outp[(size_t)i * 128 + c0] = make_float2(o0, o1);
}

// ------------------------------------ alpha0 in ORIGINAL edge order (layer0)
__global__ void k_alpha0(const int* __restrict__ ei, int E,
                         const float4* __restrict__ asrc4, const float4* __restrict__ adst4,
                         const float4* __restrict__ gm4, const float4* __restrict__ gd4,
                         float4* __restrict__ out){
    int e = blockIdx.x * 256 + threadIdx.x;
    int EP = E + NN;
    if (e >= EP) return;
    int s, d;
    if (e < E){ s = ei[e]; d = ei[E + e]; } else { s = e - E; d = s; }
    float4 as = asrc4[s], ad = adst4[d], mm = gm4[d], dn = gd4[d];
    float4 r;
    float lg;
    lg = as.x + ad.x; lg = (lg > 0.f) ? lg : NEG * lg; r.x = __expf(lg - mm.x) / dn.x;
    lg = as.y + ad.y; lg = (lg > 0.f) ? lg : NEG * lg; r.y = __expf(lg - mm.y) / dn.y;
    lg = as.z + ad.z; lg = (lg > 0.f) ? lg : NEG * lg; r.z = __expf(lg - mm.z) / dn.z;
    lg = as.w + ad.w; lg = (lg > 0.f) ? lg : NEG * lg; r.w = __expf(lg - mm.w) / dn.w;
    out[e] = r;
}

// --------------------------------------------- aggregation, 1 head x 32 ch
__global__ __launch_bounds__(256) void k_agg1(
        const float* __restrict__ h2, const float* __restrict__ asrc,
        const float* __restrict__ adst, const int* __restrict__ row_ptr,
        const unsigned short* __restrict__ ssrc, const float* __restrict__ bias,
        float* __restrict__ outp){
    int wave = (blockIdx.x * 256 + threadIdx.x) >> 6;
    int lane = threadIdx.x & 63;
    if (wave >= NN) return;
    int i = wave;
    int lo = row_ptr[i], hi = row_ptr[i + 1];

    float adv = adst[i];
    float m = -3.0e38f, sum = 0.f;
    for (int idx = lo + lane; idx < hi; idx += 64){
        int j = (int)ssrc[idx];
        float lg = asrc[j] + adv;
        lg = (lg > 0.f) ? lg : NEG * lg;
        float nm = fmaxf(m, lg);
        sum = sum * __expf(m - nm) + __expf(lg - nm);
        m = nm;
    }
    for (int off = 1; off < 64; off <<= 1){
        float mo = __shfl_xor(m, off);
        float so = __shfl_xor(sum, off);
        float nm = fmaxf(m, mo);
        float pa = (m  == nm) ? sum : sum * __expf(m - nm);
        float pb = (mo == nm) ? so  : so  * __expf(mo - nm);
        m = nm; sum = pa + pb;
    }
    float r = 1.f / sum;

    int half = lane >> 5;
    int c = lane & 31;
    float acc = 0.f;
    int idx = lo + half;
    for (; idx + 2 < hi; idx += 4){
        int j0 = (int)ssrc[idx], j1 = (int)ssrc[idx + 2];
        float v0 = h2[(size_t)j0 * 32 + c];
        float v1 = h2[(size_t)j1 * 32 + c];
        float l0 = asrc[j0] + adv; l0 = (l0 > 0.f) ? l0 : NEG * l0;
        float l1 = asrc[j1] + adv; l1 = (l1 > 0.f) ? l1 : NEG * l1;
        acc += __expf(l0 - m) * r * v0;
        acc += __expf(l1 - m) * r * v1;
    }
    for (; idx < hi; idx += 2){
        int j = (int)ssrc[idx];
        float lg = asrc[j] + adv;
        lg = (lg > 0.f) ? lg : NEG * lg;
        acc += __expf(lg - m) * r * h2[(size_t)j * 32 + c];
    }
    acc += __shfl_xor(acc, 32);
    if (half == 0) outp[(size_t)i * 32 + c] = acc + bias[c];
}

// ---------------------------------------------------------------- launcher
extern "C" void kernel_launch(void* const* d_in, const int* in_sizes, int n_in,
                              void* d_out, int out_size, void* d_ws, size_t ws_size,
                              hipStream_t stream){
    const float* x   = (const float*)d_in[0];
    const int*   ei  = (const int*)  d_in[1];
    const float* W0  = (const float*)d_in[2];
    const float* as0 = (const float*)d_in[3];
    const float* ad0 = (const float*)d_in[4];
    const float* b0  = (const float*)d_in[5];
    const float* W1  = (const float*)d_in[6];
    const float* as1 = (const float*)d_in[7];
    const float* ad1 = (const float*)d_in[8];
    const float* b1  = (const float*)d_in[9];
    const float* W2  = (const float*)d_in[10];
    const float* as2 = (const float*)d_in[11];
    const float* ad2 = (const float*)d_in[12];
    const float* b2  = (const float*)d_in[13];

    const int E  = in_sizes[1] / 2;
    const int EP = E + NN;

    char* w = (char*)d_ws;
    size_t off = 0;
    auto carve = [&](size_t bytes) -> char* {
        char* p = w + off;
        off += (bytes + 255) & ~(size_t)255;
        return p;
    };
    int*            bucketCount = (int*)       carve(sizeof(int) * 256);
    int*            row_ptr = (int*)           carve(sizeof(int) * (NN + 1));
    unsigned short* ssrc    = (unsigned short*)carve(sizeof(short) * (size_t)EP);
    float*          hbuf    = (float*)         carve(sizeof(float) * (size_t)NN * 128);
    unsigned short* hb16    = (unsigned short*)carve(sizeof(short) * (size_t)NN * 128);
    float*          post    = (float*)         carve(sizeof(float) * (size_t)NN * 128);
    float*          asrc    = (float*)         carve(sizeof(float) * NN * 4);
    float*          adst    = (float*)         carve(sizeof(float) * NN * 4);
    float*          gm      = (float*)         carve(sizeof(float) * NN * 4);
    float*          gdenom  = (float*)         carve(sizeof(float) * NN * 4);
    // tmp (16 MB, 256 buckets x 16384 u32) aliases post: fully consumed by
    // k_bucket_csr before agg4 layer-0 first writes post (stream-ordered).
    unsigned*       tmp     = (unsigned*)post;

    float* out_alpha = (float*)d_out;                  // [EP, 4]
    float* out_final = (float*)d_out + (size_t)EP * 4; // [NN, 32]

    const int edgeBlocks = (EP + 255) / 256;
    const int waveBlocks = (NN + 3) / 4;
    const dim3 gemmGrid128((NN + 63) / 64, 2);
    const dim3 gemmGrid32((NN + 63) / 64, 1);

    // ---- CSR build: LDS-staged two-pass counting sort by dst
    k_zero      <<<1, 256, 0, stream>>>(bucketCount, 256);
    k_binning   <<<(EP + TILE - 1) / TILE, 256, 0, stream>>>(ei, E, bucketCount, tmp);
    k_bucket_csr<<<256, 256, 0, stream>>>(EP, bucketCount, tmp, row_ptr, ssrc);

    // ---- layer 0
    k_gemm<64><<<gemmGrid128, 256, 0, stream>>>(x, W0, hbuf, hb16, NN, 128);
    k_nodealpha<<<(NN * 4 + 255) / 256, 256, 0, stream>>>(hbuf, as0, ad0, asrc, adst, 4, 32);
    k_agg4<<<waveBlocks, 256, 0, stream>>>((const unsigned*)hb16, asrc, adst, row_ptr,
                                           ssrc, b0, post, gm, gdenom, 1);
    k_alpha0<<<edgeBlocks, 256, 0, stream>>>(ei, E, (const float4*)asrc, (const float4*)adst,
                                             (const float4*)gm, (const float4*)gdenom,
                                             (float4*)out_alpha);

    // ---- layer 1
    k_gemm<64><<<gemmGrid128, 256, 0, stream>>>(post, W1, hbuf, hb16, NN, 128);
    k_nodealpha<<<(NN * 4 + 255) / 256, 256, 0, stream>>>(hbuf, as1, ad1, asrc, adst, 4, 32);
    k_agg4<<<waveBlocks, 256, 0, stream>>>((const unsigned*)hb16, asrc, adst, row_ptr,
                                           ssrc, b1, post, gm, gdenom, 0);

    // ---- layer 2 (1 head, 32 out, no concat/ELU)
    k_gemm<32><<<gemmGrid32, 256, 0, stream>>>(post, W2, hbuf, nullptr, NN, 32);
    k_nodealpha<<<(NN + 255) / 256, 256, 0, stream>>>(hbuf, as2, ad2, asrc, adst, 1, 32);
    k_agg1<<<waveBlocks, 256, 0, stream>>>(hbuf, asrc, adst, row_ptr, ssrc, b2, out_final);
}

// Round 4
// 499.574 us; speedup vs baseline: 1.9830x; 1.0001x over previous
//
#include <hip/hip_runtime.h>
#include <math.h>

#define NN 50000
#define NEG 0.2f
#define TILE 4096      // edges per binning block

__device__ __forceinline__ unsigned short f2bf(float f){
    unsigned u = __float_as_uint(f);
    u += 0x7fffu + ((u >> 16) & 1u);   // round-to-nearest-even
    return (unsigned short)(u >> 16);
}
__device__ __forceinline__ float bf2f(unsigned short v){
    return __uint_as_float(((unsigned)v) << 16);
}

// exclusive scan of 256 values across a 256-thread block
__device__ __forceinline__ int excl_scan_256(int v, int* buf, int tid){
    buf[tid] = v;
    __syncthreads();
#pragma unroll
    for (int off = 1; off < 256; off <<= 1){
        int t = (tid >= off) ? buf[tid - off] : 0;
        __syncthreads();
        buf[tid] += t;
        __syncthreads();
    }
    return buf[tid] - v;
}

// ---------------------------------------------------------------- utilities
__global__ void k_zero(int* p, int n){
    int i = blockIdx.x * 256 + threadIdx.x;
    if (i < n) p[i] = 0;
}

// ---------------------- CSR build pass 1: coarse binning (bucket = dst>>8)
__global__ __launch_bounds__(256) void k_binning(const int* __restrict__ ei, int E,
        int* __restrict__ bucketCount, unsigned* __restrict__ tmp){
    __shared__ unsigned stage[TILE];
    __shared__ int hist[256], sbuf[256], exs[256], cur[256], gbase[256];
    int tid = threadIdx.x;
    int EP = E + NN;
    int tileBase = blockIdx.x * TILE;
    int cnt = min(TILE, EP - tileBase);

    hist[tid] = 0;
    __syncthreads();

    unsigned packed[16];
#pragma unroll
    for (int k = 0; k < 16; ++k){
        int e = tileBase + tid + (k << 8);
        unsigned p = 0xffffffffu;
        if (e < EP){
            int s, d;
            if (e < E){ s = ei[e]; d = ei[E + e]; } else { s = e - E; d = s; }
            p = ((unsigned)d << 16) | (unsigned)s;
            atomicAdd(&hist[d >> 8], 1);
        }
        packed[k] = p;
    }
    __syncthreads();
    int h = hist[tid];
    int ex = excl_scan_256(h, sbuf, tid);
    exs[tid] = ex;
    cur[tid] = ex;
    __syncthreads();
#pragma unroll
    for (int k = 0; k < 16; ++k){
        unsigned p = packed[k];
        if (p != 0xffffffffu){
            int b = p >> 24;
            int pos = atomicAdd(&cur[b], 1);
            stage[pos] = p;
        }
    }
    gbase[tid] = atomicAdd(&bucketCount[tid], h);
    __syncthreads();
    for (int i = tid; i < cnt; i += 256){
        unsigned p = stage[i];
        int b = p >> 24;
        tmp[(b << 14) + gbase[b] + (i - exs[b])] = p;
    }
}

// ---------------------- CSR build pass 2: per-bucket fine CSR
__global__ __launch_bounds__(256) void k_bucket_csr(int EP,
        const int* __restrict__ bucketCount, const unsigned* __restrict__ tmp,
        int* __restrict__ row_ptr, unsigned short* __restrict__ ssrc){
    __shared__ int sbuf[256], deg[256], cur[256];
    __shared__ int baseSh, nSh;
    int b = blockIdx.x;
    int tid = threadIdx.x;
    int c = bucketCount[tid];
    int exb = excl_scan_256(c, sbuf, tid);
    if (tid == b){ baseSh = exb; nSh = c; }
    deg[tid] = 0;
    __syncthreads();
    int base = baseSh, n = nSh;
    const unsigned* tb = tmp + ((size_t)b << 14);
    for (int i = tid; i < n; i += 256)
        atomicAdd(&deg[(tb[i] >> 16) & 255], 1);
    __syncthreads();
    int d = deg[tid];
    int dx = excl_scan_256(d, sbuf, tid);
    cur[tid] = dx;
    int dst = (b << 8) + tid;
    if (dst < NN) row_ptr[dst] = base + dx;
    if (b == 0 && tid == 0) row_ptr[NN] = EP;
    __syncthreads();
    for (int i = tid; i < n; i += 256){
        unsigned p = tb[i];
        int pos = atomicAdd(&cur[(p >> 16) & 255], 1);
        ssrc[base + pos] = (unsigned short)(p & 0xffffu);
    }
}

// ---------------------------------------------------------------- fp32 GEMM
template<int TILEN>
__global__ __launch_bounds__(256) void k_gemm(const float* __restrict__ A,
                                              const float* __restrict__ B,
                                              float* __restrict__ C,
                                              unsigned short* __restrict__ Cbf,
                                              int M, int Ncol){
    const int TN = TILEN / 16;
    __shared__ __align__(16) float As[16][68];
    __shared__ __align__(16) float Bs[16][TILEN + 4];
    int tid = threadIdx.x;
    int tx = tid & 15;
    int ty = tid >> 4;
    int rowBase = blockIdx.x * 64;
    int colBase = blockIdx.y * TILEN;

    float acc[4][TN];
#pragma unroll
    for (int i = 0; i < 4; ++i)
#pragma unroll
        for (int j = 0; j < TN; ++j) acc[i][j] = 0.f;

    for (int k0 = 0; k0 < 128; k0 += 16){
        {
            int m  = tid >> 2;
            int kk = (tid & 3) << 2;
            int gm_ = rowBase + m;
            float4 v = make_float4(0.f, 0.f, 0.f, 0.f);
            if (gm_ < M) v = *(const float4*)&A[(size_t)gm_ * 128 + k0 + kk];
            As[kk + 0][m] = v.x; As[kk + 1][m] = v.y;
            As[kk + 2][m] = v.z; As[kk + 3][m] = v.w;
        }
        {
            const int per_row = TILEN / 4;
            const int nv = 16 * per_row;
            if (tid < nv){
                int kk = tid / per_row;
                int nn = (tid % per_row) * 4;
                float4 v = *(const float4*)&B[(size_t)(k0 + kk) * Ncol + colBase + nn];
                Bs[kk][nn + 0] = v.x; Bs[kk][nn + 1] = v.y;
                Bs[kk][nn + 2] = v.z; Bs[kk][nn + 3] = v.w;
            }
        }
        __syncthreads();
#pragma unroll
        for (int kk = 0; kk < 16; ++kk){
            float4 av = *(const float4*)&As[kk][ty * 4];
            float a[4] = {av.x, av.y, av.z, av.w};
            float bv[TN];
            if (TN == 4){
                float4 b4 = *(const float4*)&Bs[kk][tx * 4];
                bv[0] = b4.x; bv[1] = b4.y; bv[2] = b4.z; bv[3] = b4.w;
            } else {
                float2 b2 = *(const float2*)&Bs[kk][tx * 2];
                bv[0] = b2.x; bv[1] = b2.y;
            }
#pragma unroll
            for (int i = 0; i < 4; ++i)
#pragma unroll
                for (int j = 0; j < TN; ++j)
                    acc[i][j] += a[i] * bv[j];
        }
        __syncthreads();
    }
#pragma unroll
    for (int i = 0; i < 4; ++i){
        int r = rowBase + ty * 4 + i;
        if (r < M){
            if (TN == 4){
                float4 v = make_float4(acc[i][0], acc[i][1], acc[i][2], acc[i][3]);
                *(float4*)&C[(size_t)r * Ncol + colBase + tx * 4] = v;
                if (Cbf){
                    unsigned p0 = (unsigned)f2bf(acc[i][0]) | ((unsigned)f2bf(acc[i][1]) << 16);
                    unsigned p1 = (unsigned)f2bf(acc[i][2]) | ((unsigned)f2bf(acc[i][3]) << 16);
                    *(uint2*)&Cbf[(size_t)r * Ncol + colBase + tx * 4] = make_uint2(p0, p1);
                }
            } else {
                *(float2*)&C[(size_t)r * Ncol + colBase + tx * 2] =
                    make_float2(acc[i][0], acc[i][1]);
            }
        }
    }
}

// ------------------------------------------- per-node attention half-logits
__global__ void k_nodealpha(const float* __restrict__ h,
                            const float* __restrict__ a_s,
                            const float* __restrict__ a_d,
                            float* __restrict__ asrc, float* __restrict__ adst,
                            int H, int C){
    int t = blockIdx.x * 256 + threadIdx.x;
    if (t >= NN * H) return;
    int n = t / H, hd = t % H;
    const float* hp = h + (size_t)n * H * C + hd * C;
    float s1 = 0.f, s2 = 0.f;
    for (int c = 0; c < C; c += 4){
        float4 hv = *(const float4*)&hp[c];
        float4 av = *(const float4*)&a_s[hd * C + c];
        float4 dv = *(const float4*)&a_d[hd * C + c];
        s1 += hv.x * av.x + hv.y * av.y + hv.z * av.z + hv.w * av.w;
        s2 += hv.x * dv.x + hv.y * dv.y + hv.z * dv.z + hv.w * dv.w;
    }
    asrc[t] = s1;
    adst[t] = s2;
}

// ------------------- stats + normalized alpha (bf16) per CSR slot, 4 heads
// wave per node. pass A: online softmax (lane = slot*4 + head).
// pass B: recompute logits, store alpha = exp(lg-m)/denom as bf16, coalesced.
__global__ __launch_bounds__(256) void k_swalpha4(
        const float* __restrict__ asrc, const float* __restrict__ adst,
        const int* __restrict__ row_ptr, const unsigned short* __restrict__ ssrc,
        unsigned short* __restrict__ walpha,
        float* __restrict__ gm, float* __restrict__ gdenom, int writeStats){
    int wave = (blockIdx.x * 256 + threadIdx.x) >> 6;
    int lane = threadIdx.x & 63;
    if (wave >= NN) return;
    int i = wave;
    int lo = row_ptr[i], hi = row_ptr[i + 1];

    int hd = lane & 3;
    int s  = lane >> 2;                  // 16 slots
    float adv = adst[i * 4 + hd];
    float m = -3.0e38f, sum = 0.f;
    for (int idx = lo + s; idx < hi; idx += 16){
        unsigned j = ssrc[idx];
        float lg = asrc[j * 4u + hd] + adv;
        lg = fmaxf(lg, NEG * lg);
        float nm = fmaxf(m, lg);
        sum = sum * __expf(m - nm) + __expf(lg - nm);
        m = nm;
    }
    for (int off = 4; off < 64; off <<= 1){
        float mo = __shfl_xor(m, off);
        float so = __shfl_xor(sum, off);
        float nm = fmaxf(m, mo);
        float pa = (m  == nm) ? sum : sum * __expf(m - nm);
        float pb = (mo == nm) ? so  : so  * __expf(mo - nm);
        m = nm; sum = pa + pb;
    }
    if (writeStats && s == 0){
        gm[i * 4 + hd] = m;
        gdenom[i * 4 + hd] = sum;
    }
    float rs = 1.f / sum;
    // pass B: store alpha per slot (lanes cover 16 slots x 4 heads -> coalesced)
    for (int idx = lo + s; idx < hi; idx += 16){
        unsigned j = ssrc[idx];
        float lg = asrc[j * 4u + hd] + adv;
        lg = fmaxf(lg, NEG * lg);
        float w = __expf(lg - m) * rs;
        walpha[(unsigned)idx * 4u + hd] = f2bf(w);
    }
}

// --------------------- pure gather-FMA aggregation, 4 heads x 32 ch (bf16 h)
// wave per node: 4 edge subgroups x 16 chunk-lanes; each lane loads dwordx4
// (8 bf16 channels) of one src row. Cross-group combine via shfl_xor.
__global__ __launch_bounds__(256) void k_agg4w(
        const uint4* __restrict__ hb4,            // [NN][16] dwordx4 rows
        const unsigned short* __restrict__ walpha,
        const int* __restrict__ row_ptr, const unsigned short* __restrict__ ssrc,
        const float* __restrict__ bias, float* __restrict__ outp){
    int wave = (blockIdx.x * 256 + threadIdx.x) >> 6;
    int lane = threadIdx.x & 63;
    if (wave >= NN) return;
    int i = wave;
    int lo = row_ptr[i], hi = row_ptr[i + 1];
    int g = lane >> 4;                   // edge subgroup 0..3
    int q = lane & 15;                   // channel chunk: ch q*8..q*8+7
    int myh = q >> 2;                    // head of these channels

    float acc[8];
#pragma unroll
    for (int k = 0; k < 8; ++k) acc[k] = 0.f;

    int idx = lo;
#define AGG4_BODY(JJ, WW) {                                                   \
        uint4 gv = hb4[(unsigned)(JJ) * 16u + (unsigned)q];                   \
        float a = bf2f(WW);                                                   \
        acc[0] += a * __uint_as_float(gv.x << 16);                            \
        acc[1] += a * __uint_as_float(gv.x & 0xffff0000u);                    \
        acc[2] += a * __uint_as_float(gv.y << 16);                            \
        acc[3] += a * __uint_as_float(gv.y & 0xffff0000u);                    \
        acc[4] += a * __uint_as_float(gv.z << 16);                            \
        acc[5] += a * __uint_as_float(gv.z & 0xffff0000u);                    \
        acc[6] += a * __uint_as_float(gv.w << 16);                            \
        acc[7] += a * __uint_as_float(gv.w & 0xffff0000u); }
    for (; idx + 4 <= hi; idx += 4){
        unsigned j = ssrc[idx + g];
        unsigned short wv = walpha[(unsigned)(idx + g) * 4u + myh];
        AGG4_BODY(j, wv)
    }
    if (idx + g < hi){                   // remainder < 4
        unsigned j = ssrc[idx + g];
        unsigned short wv = walpha[(unsigned)(idx + g) * 4u + myh];
        AGG4_BODY(j, wv)
    }
#undef AGG4_BODY
#pragma unroll
    for (int k = 0; k < 8; ++k){
        acc[k] += __shfl_xor(acc[k], 16);
        acc[k] += __shfl_xor(acc[k], 32);
    }
    if (g == 0){
        int c0 = q * 8;
        float4 bA = *(const float4*)&bias[c0];
        float4 bB = *(const float4*)&bias[c0 + 4];
        float o[8] = {acc[0] + bA.x, acc[1] + bA.y, acc[2] + bA.z, acc[3] + bA.w,
                      acc[4] + bB.x, acc[5] + bB.y, acc[6] + bB.z, acc[7] + bB.w};
#pragma unroll
        for (int k = 0; k < 8; ++k)
            o[k] = (o[k] > 0.f) ? o[k] : (__expf(o[k]) - 1.f);   // ELU
        *(float4*)&outp[(size_t)i * 128 + c0]     = make_float4(o[0], o[1], o[2], o[3]);
        *(float4*)&outp[(size_t)i * 128 + c0 + 4] = make_float4(o[4], o[5], o[6], o[7]);
    }
}

// ------------------------------------ alpha0 in ORIGINAL edge order (layer0)
__global__ void k_alpha0(const int* __restrict__ ei, int E,
                         const float4* __restrict__ asrc4, const float4* __restrict__ adst4,
                         const float4* __restrict__ gm4, const float4* __restrict__ gd4,
                         float4* __restrict__ out){
    int e = blockIdx.x * 256 + threadIdx.x;
    int EP = E + NN;
    if (e >= EP) return;
    int s, d;
    if (e < E){ s = ei[e]; d = ei[E + e]; } else { s = e - E; d = s; }
    float4 as = asrc4[s], ad = adst4[d], mm = gm4[d], dn = gd4[d];
    float4 r;
    float lg;
    lg = as.x + ad.x; lg = fmaxf(lg, NEG * lg); r.x = __expf(lg - mm.x) / dn.x;
    lg = as.y + ad.y; lg = fmaxf(lg, NEG * lg); r.y = __expf(lg - mm.y) / dn.y;
    lg = as.z + ad.z; lg = fmaxf(lg, NEG * lg); r.z = __expf(lg - mm.z) / dn.z;
    lg = as.w + ad.w; lg = fmaxf(lg, NEG * lg); r.w = __expf(lg - mm.w) / dn.w;
    out[e] = r;
}

// ------------------- stats + alpha (bf16) per CSR slot, 1 head (layer 2)
__global__ __launch_bounds__(256) void k_swalpha1(
        const float* __restrict__ asrc, const float* __restrict__ adst,
        const int* __restrict__ row_ptr, const unsigned short* __restrict__ ssrc,
        unsigned short* __restrict__ walpha1){
    int wave = (blockIdx.x * 256 + threadIdx.x) >> 6;
    int lane = threadIdx.x & 63;
    if (wave >= NN) return;
    int i = wave;
    int lo = row_ptr[i], hi = row_ptr[i + 1];

    float adv = adst[i];
    float m = -3.0e38f, sum = 0.f;
    for (int idx = lo + lane; idx < hi; idx += 64){
        unsigned j = ssrc[idx];
        float lg = asrc[j] + adv;
        lg = fmaxf(lg, NEG * lg);
        float nm = fmaxf(m, lg);
        sum = sum * __expf(m - nm) + __expf(lg - nm);
        m = nm;
    }
    for (int off = 1; off < 64; off <<= 1){
        float mo = __shfl_xor(m, off);
        float so = __shfl_xor(sum, off);
        float nm = fmaxf(m, mo);
        float pa = (m  == nm) ? sum : sum * __expf(m - nm);
        float pb = (mo == nm) ? so  : so  * __expf(mo - nm);
        m = nm; sum = pa + pb;
    }
    float rs = 1.f / sum;
    for (int idx = lo + lane; idx < hi; idx += 64){
        unsigned j = ssrc[idx];
        float lg = asrc[j] + adv;
        lg = fmaxf(lg, NEG * lg);
        walpha1[idx] = f2bf(__expf(lg - m) * rs);
    }
}

// --------------------- pure gather-FMA aggregation, 1 head x 32 ch (fp32 h)
// 8 edge subgroups x 8 chunk-lanes; each lane loads float4 (4 channels).
__global__ __launch_bounds__(256) void k_agg1w(
        const float4* __restrict__ h24,           // [NN][8] float4 rows
        const unsigned short* __restrict__ walpha1,
        const int* __restrict__ row_ptr, const unsigned short* __restrict__ ssrc,
        const float* __restrict__ bias, float* __restrict__ outp){
    int wave = (blockIdx.x * 256 + threadIdx.x) >> 6;
    int lane = threadIdx.x & 63;
    if (wave >= NN) return;
    int i = wave;
    int lo = row_ptr[i], hi = row_ptr[i + 1];
    int g = lane >> 3;                   // edge subgroup 0..7
    int q = lane & 7;                    // channel chunk: ch q*4..q*4+3

    float acc[4] = {0.f, 0.f, 0.f, 0.f};
    int idx = lo;
    for (; idx + 8 <= hi; idx += 8){
        unsigned j = ssrc[idx + g];
        float a = bf2f(walpha1[(unsigned)(idx + g)]);
        float4 v = h24[(unsigned)j * 8u + (unsigned)q];
        acc[0] += a * v.x; acc[1] += a * v.y;
        acc[2] += a * v.z; acc[3] += a * v.w;
    }
    if (idx + g < hi){                   // remainder < 8
        unsigned j = ssrc[idx + g];
        float a = bf2f(walpha1[(unsigned)(idx + g)]);
        float4 v = h24[(unsigned)j * 8u + (unsigned)q];
        acc[0] += a * v.x; acc[1] += a * v.y;
        acc[2] += a * v.z; acc[3] += a * v.w;
    }
#pragma unroll
    for (int k = 0; k < 4; ++k){
        acc[k] += __shfl_xor(acc[k], 8);
        acc[k] += __shfl_xor(acc[k], 16);
        acc[k] += __shfl_xor(acc[k], 32);
    }
    if (g == 0){
        float4 b = *(const float4*)&bias[q * 4];
        *(float4*)&outp[(size_t)i * 32 + q * 4] =
            make_float4(acc[0] + b.x, acc[1] + b.y, acc[2] + b.z, acc[3] + b.w);
    }
}

// ---------------------------------------------------------------- launcher
extern "C" void kernel_launch(void* const* d_in, const int* in_sizes, int n_in,
                              void* d_out, int out_size, void* d_ws, size_t ws_size,
                              hipStream_t stream){
    const float* x   = (const float*)d_in[0];
    const int*   ei  = (const int*)  d_in[1];
    const float* W0  = (const float*)d_in[2];
    const float* as0 = (const float*)d_in[3];
    const float* ad0 = (const float*)d_in[4];
    const float* b0  = (const float*)d_in[5];
    const float* W1  = (const float*)d_in[6];
    const float* as1 = (const float*)d_in[7];
    const float* ad1 = (const float*)d_in[8];
    const float* b1  = (const float*)d_in[9];
    const float* W2  = (const float*)d_in[10];
    const float* as2 = (const float*)d_in[11];
    const float* ad2 = (const float*)d_in[12];
    const float* b2  = (const float*)d_in[13];

    const int E  = in_sizes[1] / 2;
    const int EP = E + NN;

    char* w = (char*)d_ws;
    size_t off = 0;
    auto carve = [&](size_t bytes) -> char* {
        char* p = w + off;
        off += (bytes + 255) & ~(size_t)255;
        return p;
    };
    int*            bucketCount = (int*)       carve(sizeof(int) * 256);
    int*            row_ptr = (int*)           carve(sizeof(int) * (NN + 1));
    unsigned short* ssrc    = (unsigned short*)carve(sizeof(short) * (size_t)EP);
    float*          hbuf    = (float*)         carve(sizeof(float) * (size_t)NN * 128);
    unsigned short* hb16    = (unsigned short*)carve(sizeof(short) * (size_t)NN * 128);
    float*          post    = (float*)         carve(sizeof(float) * (size_t)NN * 128);
    float*          asrc    = (float*)         carve(sizeof(float) * NN * 4);
    float*          adst    = (float*)         carve(sizeof(float) * NN * 4);
    float*          gm      = (float*)         carve(sizeof(float) * NN * 4);
    float*          gdenom  = (float*)         carve(sizeof(float) * NN * 4);
    unsigned short* walpha  = (unsigned short*)carve(sizeof(short) * (size_t)EP * 4);
    // aliases: tmp (16MB) on post (25.6MB) — consumed before agg4w writes post;
    // walpha1 on walpha — layers 0/1 done with walpha before layer 2 writes it.
    unsigned*       tmp     = (unsigned*)post;
    unsigned short* walpha1 = walpha;

    float* out_alpha = (float*)d_out;                  // [EP, 4]
    float* out_final = (float*)d_out + (size_t)EP * 4; // [NN, 32]

    const int edgeBlocks = (EP + 255) / 256;
    const int waveBlocks = (NN + 3) / 4;
    const dim3 gemmGrid128((NN + 63) / 64, 2);
    const dim3 gemmGrid32((NN + 63) / 64, 1);

    // ---- CSR build: LDS-staged two-pass counting sort by dst
    k_zero      <<<1, 256, 0, stream>>>(bucketCount, 256);
    k_binning   <<<(EP + TILE - 1) / TILE, 256, 0, stream>>>(ei, E, bucketCount, tmp);
    k_bucket_csr<<<256, 256, 0, stream>>>(EP, bucketCount, tmp, row_ptr, ssrc);

    // ---- layer 0
    k_gemm<64><<<gemmGrid128, 256, 0, stream>>>(x, W0, hbuf, hb16, NN, 128);
    k_nodealpha<<<(NN * 4 + 255) / 256, 256, 0, stream>>>(hbuf, as0, ad0, asrc, adst, 4, 32);
    k_swalpha4<<<waveBlocks, 256, 0, stream>>>(asrc, adst, row_ptr, ssrc, walpha,
                                               gm, gdenom, 1);
    k_agg4w<<<waveBlocks, 256, 0, stream>>>((const uint4*)hb16, walpha, row_ptr,
                                            ssrc, b0, post);
    k_alpha0<<<edgeBlocks, 256, 0, stream>>>(ei, E, (const float4*)asrc, (const float4*)adst,
                                             (const float4*)gm, (const float4*)gdenom,
                                             (float4*)out_alpha);

    // ---- layer 1
    k_gemm<64><<<gemmGrid128, 256, 0, stream>>>(post, W1, hbuf, hb16, NN, 128);
    k_nodealpha<<<(NN * 4 + 255) / 256, 256, 0, stream>>>(hbuf, as1, ad1, asrc, adst, 4, 32);
    k_swalpha4<<<waveBlocks, 256, 0, stream>>>(asrc, adst, row_ptr, ssrc, walpha,
                                               gm, gdenom, 0);
    k_agg4w<<<waveBlocks, 256, 0, stream>>>((const uint4*)hb16, walpha, row_ptr,
                                            ssrc, b1, post);

    // ---- layer 2 (1 head, 32 out, no concat/ELU)
    k_gemm<32><<<gemmGrid32, 256, 0, stream>>>(post, W2, hbuf, nullptr, NN, 32);
    k_nodealpha<<<(NN + 255) / 256, 256, 0, stream>>>(hbuf, as2, ad2, asrc, adst, 1, 32);
    k_swalpha1<<<waveBlocks, 256, 0, stream>>>(asrc, adst, row_ptr, ssrc, walpha1);
    k_agg1w<<<waveBlocks, 256, 0, stream>>>((const float4*)hbuf, walpha1, row_ptr,
                                            ssrc, b2, out_final);
}

// Round 5
// 481.406 us; speedup vs baseline: 2.0579x; 1.0377x over previous
//
#include <hip/hip_runtime.h>
#include <math.h>

#define NN 50000
#define NEG 0.2f
#define TILE 4096      // edges per binning block

typedef __attribute__((ext_vector_type(8))) short short8;
typedef __attribute__((ext_vector_type(4))) float f32x4;

__device__ __forceinline__ unsigned short f2bf(float f){
    unsigned u = __float_as_uint(f);
    u += 0x7fffu + ((u >> 16) & 1u);   // round-to-nearest-even
    return (unsigned short)(u >> 16);
}
__device__ __forceinline__ float bf2f(unsigned short v){
    return __uint_as_float(((unsigned)v) << 16);
}

// exclusive scan of 256 values across a 256-thread block
__device__ __forceinline__ int excl_scan_256(int v, int* buf, int tid){
    buf[tid] = v;
    __syncthreads();
#pragma unroll
    for (int off = 1; off < 256; off <<= 1){
        int t = (tid >= off) ? buf[tid - off] : 0;
        __syncthreads();
        buf[tid] += t;
        __syncthreads();
    }
    return buf[tid] - v;
}

// ---------------------------------------------------------------- utilities
__global__ void k_zero(int* p, int n){
    int i = blockIdx.x * 256 + threadIdx.x;
    if (i < n) p[i] = 0;
}

// ---------------------- CSR build pass 1: coarse binning (bucket = dst>>8)
__global__ __launch_bounds__(256) void k_binning(const int* __restrict__ ei, int E,
        int* __restrict__ bucketCount, unsigned* __restrict__ tmp){
    __shared__ unsigned stage[TILE];
    __shared__ int hist[256], sbuf[256], exs[256], cur[256], gbase[256];
    int tid = threadIdx.x;
    int EP = E + NN;
    int tileBase = blockIdx.x * TILE;
    int cnt = min(TILE, EP - tileBase);

    hist[tid] = 0;
    __syncthreads();

    unsigned packed[16];
#pragma unroll
    for (int k = 0; k < 16; ++k){
        int e = tileBase + tid + (k << 8);
        unsigned p = 0xffffffffu;
        if (e < EP){
            int s, d;
            if (e < E){ s = ei[e]; d = ei[E + e]; } else { s = e - E; d = s; }
            p = ((unsigned)d << 16) | (unsigned)s;
            atomicAdd(&hist[d >> 8], 1);
        }
        packed[k] = p;
    }
    __syncthreads();
    int h = hist[tid];
    int ex = excl_scan_256(h, sbuf, tid);
    exs[tid] = ex;
    cur[tid] = ex;
    __syncthreads();
#pragma unroll
    for (int k = 0; k < 16; ++k){
        unsigned p = packed[k];
        if (p != 0xffffffffu){
            int b = p >> 24;
            int pos = atomicAdd(&cur[b], 1);
            stage[pos] = p;
        }
    }
    gbase[tid] = atomicAdd(&bucketCount[tid], h);
    __syncthreads();
    for (int i = tid; i < cnt; i += 256){
        unsigned p = stage[i];
        int b = p >> 24;
        tmp[(b << 14) + gbase[b] + (i - exs[b])] = p;
    }
}

// ---------------------- CSR build pass 2: per-bucket fine CSR
__global__ __launch_bounds__(256) void k_bucket_csr(int EP,
        const int* __restrict__ bucketCount, const unsigned* __restrict__ tmp,
        int* __restrict__ row_ptr, unsigned short* __restrict__ ssrc){
    __shared__ int sbuf[256], deg[256], cur[256];
    __shared__ int baseSh, nSh;
    int b = blockIdx.x;
    int tid = threadIdx.x;
    int c = bucketCount[tid];
    int exb = excl_scan_256(c, sbuf, tid);
    if (tid == b){ baseSh = exb; nSh = c; }
    deg[tid] = 0;
    __syncthreads();
    int base = baseSh, n = nSh;
    const unsigned* tb = tmp + ((size_t)b << 14);
    for (int i = tid; i < n; i += 256)
        atomicAdd(&deg[(tb[i] >> 16) & 255], 1);
    __syncthreads();
    int d = deg[tid];
    int dx = excl_scan_256(d, sbuf, tid);
    cur[tid] = dx;
    int dst = (b << 8) + tid;
    if (dst < NN) row_ptr[dst] = base + dx;
    if (b == 0 && tid == 0) row_ptr[NN] = EP;
    __syncthreads();
    for (int i = tid; i < n; i += 256){
        unsigned p = tb[i];
        int pos = atomicAdd(&cur[(p >> 16) & 255], 1);
        ssrc[base + pos] = (unsigned short)(p & 0xffffu);
    }
}

// ------------------------- pack W -> B^T bf16 hi/lo tables (one-shot, tiny)
// Whi/Wlo layout: [Ncol][128] so a lane's 8 k-elems are contiguous (16B).
__global__ void k_packW(const float* __restrict__ W0, const float* __restrict__ W1,
                        const float* __restrict__ W2,
                        unsigned short* __restrict__ h0, unsigned short* __restrict__ l0,
                        unsigned short* __restrict__ h1, unsigned short* __restrict__ l1,
                        unsigned short* __restrict__ h2, unsigned short* __restrict__ l2){
    int t = blockIdx.x * 256 + threadIdx.x;
    const float* W; unsigned short *ph, *pl; int Ncol; int u;
    if (t < 16384){ W = W0; ph = h0; pl = l0; Ncol = 128; u = t; }
    else if (t < 32768){ W = W1; ph = h1; pl = l1; Ncol = 128; u = t - 16384; }
    else if (t < 36864){ W = W2; ph = h2; pl = l2; Ncol = 32;  u = t - 32768; }
    else return;
    int n = u >> 7, k = u & 127;
    float f = W[k * Ncol + n];
    unsigned short hi = f2bf(f);
    unsigned short lo = f2bf(f - bf2f(hi));
    ph[n * 128 + k] = hi;
    pl[n * 128 + k] = lo;
}

// -------------------------------------- MFMA GEMM: C[M,NT*16] = A[M,128]@B
// hi/lo-compensated bf16 (3 MFMAs: AhiBhi + AloBhi + AhiBlo) ~= fp32 accuracy.
// Wave computes a 16-row x NT*16-col strip; block = 4 waves = 64 rows.
template<int NT>
__global__ __launch_bounds__(256) void k_gemm_mfma(
        const float* __restrict__ A,
        const unsigned short* __restrict__ Bhi,   // [NT*16][128] bf16 (B^T)
        const unsigned short* __restrict__ Blo,
        float* __restrict__ C, unsigned short* __restrict__ Cbf, int M){
    const int Ncol = NT * 16;
    int wave = threadIdx.x >> 6;
    int lane = threadIdx.x & 63;
    int r    = lane & 15;
    int oct  = lane >> 4;
    int rowBase = blockIdx.x * 64 + wave * 16;

    f32x4 acc[NT];
#pragma unroll
    for (int c = 0; c < NT; ++c) acc[c] = (f32x4){0.f, 0.f, 0.f, 0.f};

    int lrow = rowBase + r; if (lrow > M - 1) lrow = M - 1;
    const float* arow = A + (size_t)lrow * 128;

    for (int t = 0; t < 4; ++t){
        int k0 = t * 32 + oct * 8;
        float4 a0 = *(const float4*)&arow[k0];
        float4 a1 = *(const float4*)&arow[k0 + 4];
        float av[8] = {a0.x, a0.y, a0.z, a0.w, a1.x, a1.y, a1.z, a1.w};
        short8 ahi, alo;
#pragma unroll
        for (int j = 0; j < 8; ++j){
            unsigned short h = f2bf(av[j]);
            unsigned short l = f2bf(av[j] - bf2f(h));
            ahi[j] = (short)h; alo[j] = (short)l;
        }
#pragma unroll
        for (int c = 0; c < NT; ++c){
            short8 bhi = *(const short8*)&Bhi[(c * 16 + r) * 128 + k0];
            short8 blo = *(const short8*)&Blo[(c * 16 + r) * 128 + k0];
            acc[c] = __builtin_amdgcn_mfma_f32_16x16x32_bf16(ahi, bhi, acc[c], 0, 0, 0);
            acc[c] = __builtin_amdgcn_mfma_f32_16x16x32_bf16(alo, bhi, acc[c], 0, 0, 0);
            acc[c] = __builtin_amdgcn_mfma_f32_16x16x32_bf16(ahi, blo, acc[c], 0, 0, 0);
        }
    }
    // C/D layout: col = lane&15, row = oct*4 + reg   [verified m89/m91]
#pragma unroll
    for (int c = 0; c < NT; ++c){
#pragma unroll
        for (int reg = 0; reg < 4; ++reg){
            int row = rowBase + oct * 4 + reg;
            if (row < M){
                int col = c * 16 + r;
                float v = acc[c][reg];
                C[(size_t)row * Ncol + col] = v;
                if (Cbf) Cbf[(size_t)row * Ncol + col] = f2bf(v);
            }
        }
    }
}

// ------------------------------------------- per-node attention half-logits
__global__ void k_nodealpha(const float* __restrict__ h,
                            const float* __restrict__ a_s,
                            const float* __restrict__ a_d,
                            float* __restrict__ asrc, float* __restrict__ adst,
                            int H, int C){
    int t = blockIdx.x * 256 + threadIdx.x;
    if (t >= NN * H) return;
    int n = t / H, hd = t % H;
    const float* hp = h + (size_t)n * H * C + hd * C;
    float s1 = 0.f, s2 = 0.f;
    for (int c = 0; c < C; c += 4){
        float4 hv = *(const float4*)&hp[c];
        float4 av = *(const float4*)&a_s[hd * C + c];
        float4 dv = *(const float4*)&a_d[hd * C + c];
        s1 += hv.x * av.x + hv.y * av.y + hv.z * av.z + hv.w * av.w;
        s2 += hv.x * dv.x + hv.y * dv.y + hv.z * dv.z + hv.w * dv.w;
    }
    asrc[t] = s1;
    adst[t] = s2;
}

// ---------------- merged aggregation, 4 heads x 32 ch: stats + gather-FMA
// pass1: online softmax (lane = slot*4 + head, 16 slots).
// pass2: 4 edge subgroups x 16 chunk-lanes, alpha recomputed inline
// (1 exp per lane per 4-edge iter), dwordx4 bf16 gather, shfl combine.
__global__ __launch_bounds__(256) void k_agg4m(
        const uint4* __restrict__ hb4,            // [NN][16] dwordx4 bf16 rows
        const float* __restrict__ asrc, const float* __restrict__ adst,
        const int* __restrict__ row_ptr, const unsigned short* __restrict__ ssrc,
        const float* __restrict__ bias, float* __restrict__ outp,
        float* __restrict__ gm, float* __restrict__ gdenom, int writeStats){
    int wave = (blockIdx.x * 256 + threadIdx.x) >> 6;
    int lane = threadIdx.x & 63;
    if (wave >= NN) return;
    int i = wave;
    int lo = row_ptr[i], hi = row_ptr[i + 1];

    // ---- pass 1
    int hd = lane & 3;
    int s  = lane >> 2;
    float adv1 = adst[i * 4 + hd];
    float m = -3.0e38f, sum = 0.f;
    for (int idx = lo + s; idx < hi; idx += 16){
        unsigned j = ssrc[idx];
        float lg = asrc[j * 4u + hd] + adv1;
        lg = fmaxf(lg, NEG * lg);
        float nm = fmaxf(m, lg);
        sum = sum * __expf(m - nm) + __expf(lg - nm);
        m = nm;
    }
    for (int off = 4; off < 64; off <<= 1){
        float mo = __shfl_xor(m, off);
        float so = __shfl_xor(sum, off);
        float nm = fmaxf(m, mo);
        float pa = (m  == nm) ? sum : sum * __expf(m - nm);
        float pb = (mo == nm) ? so  : so  * __expf(mo - nm);
        m = nm; sum = pa + pb;
    }
    if (writeStats && s == 0){
        gm[i * 4 + hd] = m;
        gdenom[i * 4 + hd] = sum;
    }

    // ---- pass 2
    int g = lane >> 4;                   // edge subgroup 0..3
    int q = lane & 15;                   // channel chunk: ch q*8..q*8+7
    int myh = q >> 2;                    // head of these channels
    float mh = __shfl(m, myh);
    float rs = 1.f / __shfl(sum, myh);
    float adv = adst[i * 4 + myh];

    float acc[8];
#pragma unroll
    for (int k = 0; k < 8; ++k) acc[k] = 0.f;

    int idx = lo;
#define AGG4_BODY(JJ) {                                                       \
        float lg = asrc[(JJ) * 4u + myh] + adv;                               \
        lg = fmaxf(lg, NEG * lg);                                             \
        float a = __expf(lg - mh) * rs;                                       \
        uint4 gv = hb4[(JJ) * 16u + (unsigned)q];                             \
        acc[0] += a * __uint_as_float(gv.x << 16);                            \
        acc[1] += a * __uint_as_float(gv.x & 0xffff0000u);                    \
        acc[2] += a * __uint_as_float(gv.y << 16);                            \
        acc[3] += a * __uint_as_float(gv.y & 0xffff0000u);                    \
        acc[4] += a * __uint_as_float(gv.z << 16);                            \
        acc[5] += a * __uint_as_float(gv.z & 0xffff0000u);                    \
        acc[6] += a * __uint_as_float(gv.w << 16);                            \
        acc[7] += a * __uint_as_float(gv.w & 0xffff0000u); }
    for (; idx + 4 <= hi; idx += 4){
        unsigned j = ssrc[idx + g];
        AGG4_BODY(j)
    }
    if (idx + g < hi){
        unsigned j = ssrc[idx + g];
        AGG4_BODY(j)
    }
#undef AGG4_BODY
#pragma unroll
    for (int k = 0; k < 8; ++k){
        acc[k] += __shfl_xor(acc[k], 16);
        acc[k] += __shfl_xor(acc[k], 32);
    }
    if (g == 0){
        int c0 = q * 8;
        float4 bA = *(const float4*)&bias[c0];
        float4 bB = *(const float4*)&bias[c0 + 4];
        float o[8] = {acc[0] + bA.x, acc[1] + bA.y, acc[2] + bA.z, acc[3] + bA.w,
                      acc[4] + bB.x, acc[5] + bB.y, acc[6] + bB.z, acc[7] + bB.w};
#pragma unroll
        for (int k = 0; k < 8; ++k)
            o[k] = (o[k] > 0.f) ? o[k] : (__expf(o[k]) - 1.f);   // ELU
        *(float4*)&outp[(size_t)i * 128 + c0]     = make_float4(o[0], o[1], o[2], o[3]);
        *(float4*)&outp[(size_t)i * 128 + c0 + 4] = make_float4(o[4], o[5], o[6], o[7]);
    }
}

// ------------------------------------ alpha0 in ORIGINAL edge order (layer0)
__global__ void k_alpha0(const int* __restrict__ ei, int E,
                         const float4* __restrict__ asrc4, const float4* __restrict__ adst4,
                         const float4* __restrict__ gm4, const float4* __restrict__ gd4,
                         float4* __restrict__ out){
    int e = blockIdx.x * 256 + threadIdx.x;
    int EP = E + NN;
    if (e >= EP) return;
    int s, d;
    if (e < E){ s = ei[e]; d = ei[E + e]; } else { s = e - E; d = s; }
    float4 as = asrc4[s], ad = adst4[d], mm = gm4[d], dn = gd4[d];
    float4 r;
    float lg;
    lg = as.x + ad.x; lg = fmaxf(lg, NEG * lg); r.x = __expf(lg - mm.x) / dn.x;
    lg = as.y + ad.y; lg = fmaxf(lg, NEG * lg); r.y = __expf(lg - mm.y) / dn.y;
    lg = as.z + ad.z; lg = fmaxf(lg, NEG * lg); r.z = __expf(lg - mm.z) / dn.z;
    lg = as.w + ad.w; lg = fmaxf(lg, NEG * lg); r.w = __expf(lg - mm.w) / dn.w;
    out[e] = r;
}

// ---------------- merged aggregation, 1 head x 32 ch (fp32 h, layer 2)
__global__ __launch_bounds__(256) void k_agg1m(
        const float4* __restrict__ h24,           // [NN][8] float4 rows
        const float* __restrict__ asrc, const float* __restrict__ adst,
        const int* __restrict__ row_ptr, const unsigned short* __restrict__ ssrc,
        const float* __restrict__ bias, float* __restrict__ outp){
    int wave = (blockIdx.x * 256 + threadIdx.x) >> 6;
    int lane = threadIdx.x & 63;
    if (wave >= NN) return;
    int i = wave;
    int lo = row_ptr[i], hi = row_ptr[i + 1];

    float adv = adst[i];
    float m = -3.0e38f, sum = 0.f;
    for (int idx = lo + lane; idx < hi; idx += 64){
        unsigned j = ssrc[idx];
        float lg = asrc[j] + adv;
        lg = fmaxf(lg, NEG * lg);
        float nm = fmaxf(m, lg);
        sum = sum * __expf(m - nm) + __expf(lg - nm);
        m = nm;
    }
    for (int off = 1; off < 64; off <<= 1){
        float mo = __shfl_xor(m, off);
        float so = __shfl_xor(sum, off);
        float nm = fmaxf(m, mo);
        float pa = (m  == nm) ? sum : sum * __expf(m - nm);
        float pb = (mo == nm) ? so  : so  * __expf(mo - nm);
        m = nm; sum = pa + pb;
    }
    float rs = 1.f / sum;

    int g = lane >> 3;                   // edge subgroup 0..7
    int q = lane & 7;                    // channel chunk: ch q*4..q*4+3
    float acc[4] = {0.f, 0.f, 0.f, 0.f};
    int idx = lo;
    for (; idx + 8 <= hi; idx += 8){
        unsigned j = ssrc[idx + g];
        float lg = asrc[j] + adv;
        lg = fmaxf(lg, NEG * lg);
        float a = __expf(lg - m) * rs;
        float4 v = h24[(unsigned)j * 8u + (unsigned)q];
        acc[0] += a * v.x; acc[1] += a * v.y;
        acc[2] += a * v.z; acc[3] += a * v.w;
    }
    if (idx + g < hi){
        unsigned j = ssrc[idx + g];
        float lg = asrc[j] + adv;
        lg = fmaxf(lg, NEG * lg);
        float a = __expf(lg - m) * rs;
        float4 v = h24[(unsigned)j * 8u + (unsigned)q];
        acc[0] += a * v.x; acc[1] += a * v.y;
        acc[2] += a * v.z; acc[3] += a * v.w;
    }
#pragma unroll
    for (int k = 0; k < 4; ++k){
        acc[k] += __shfl_xor(acc[k], 8);
        acc[k] += __shfl_xor(acc[k], 16);
        acc[k] += __shfl_xor(acc[k], 32);
    }
    if (g == 0){
        float4 b = *(const float4*)&bias[q * 4];
        *(float4*)&outp[(size_t)i * 32 + q * 4] =
            make_float4(acc[0] + b.x, acc[1] + b.y, acc[2] + b.z, acc[3] + b.w);
    }
}

// ---------------------------------------------------------------- launcher
extern "C" void kernel_launch(void* const* d_in, const int* in_sizes, int n_in,
                              void* d_out, int out_size, void* d_ws, size_t ws_size,
                              hipStream_t stream){
    const float* x   = (const float*)d_in[0];
    const int*   ei  = (const int*)  d_in[1];
    const float* W0  = (const float*)d_in[2];
    const float* as0 = (const float*)d_in[3];
    const float* ad0 = (const float*)d_in[4];
    const float* b0  = (const float*)d_in[5];
    const float* W1  = (const float*)d_in[6];
    const float* as1 = (const float*)d_in[7];
    const float* ad1 = (const float*)d_in[8];
    const float* b1  = (const float*)d_in[9];
    const float* W2  = (const float*)d_in[10];
    const float* as2 = (const float*)d_in[11];
    const float* ad2 = (const float*)d_in[12];
    const float* b2  = (const float*)d_in[13];

    const int E  = in_sizes[1] / 2;
    const int EP = E + NN;

    char* w = (char*)d_ws;
    size_t off = 0;
    auto carve = [&](size_t bytes) -> char* {
        char* p = w + off;
        off += (bytes + 255) & ~(size_t)255;
        return p;
    };
    int*            bucketCount = (int*)       carve(sizeof(int) * 256);
    int*            row_ptr = (int*)           carve(sizeof(int) * (NN + 1));
    unsigned short* ssrc    = (unsigned short*)carve(sizeof(short) * (size_t)EP);
    float*          hbuf    = (float*)         carve(sizeof(float) * (size_t)NN * 128);
    unsigned short* hb16    = (unsigned short*)carve(sizeof(short) * (size_t)NN * 128);
    float*          post    = (float*)         carve(sizeof(float) * (size_t)NN * 128);
    float*          asrc    = (float*)         carve(sizeof(float) * NN * 4);
    float*          adst    = (float*)         carve(sizeof(float) * NN * 4);
    float*          gm      = (float*)         carve(sizeof(float) * NN * 4);
    float*          gdenom  = (float*)         carve(sizeof(float) * NN * 4);
    unsigned short* Whi0    = (unsigned short*)carve(sizeof(short) * 16384);
    unsigned short* Wlo0    = (unsigned short*)carve(sizeof(short) * 16384);
    unsigned short* Whi1    = (unsigned short*)carve(sizeof(short) * 16384);
    unsigned short* Wlo1    = (unsigned short*)carve(sizeof(short) * 16384);
    unsigned short* Whi2    = (unsigned short*)carve(sizeof(short) * 4096);
    unsigned short* Wlo2    = (unsigned short*)carve(sizeof(short) * 4096);
    // tmp (16MB) aliases post (25.6MB): consumed by k_bucket_csr before
    // layer-0 agg4m first writes post (stream-ordered).
    unsigned*       tmp     = (unsigned*)post;

    float* out_alpha = (float*)d_out;                  // [EP, 4]
    float* out_final = (float*)d_out + (size_t)EP * 4; // [NN, 32]

    const int edgeBlocks = (EP + 255) / 256;
    const int waveBlocks = (NN + 3) / 4;
    const int gemmBlocks = (NN + 63) / 64;

    // ---- CSR build + weight pack
    k_zero      <<<1, 256, 0, stream>>>(bucketCount, 256);
    k_binning   <<<(EP + TILE - 1) / TILE, 256, 0, stream>>>(ei, E, bucketCount, tmp);
    k_bucket_csr<<<256, 256, 0, stream>>>(EP, bucketCount, tmp, row_ptr, ssrc);
    k_packW     <<<144, 256, 0, stream>>>(W0, W1, W2, Whi0, Wlo0, Whi1, Wlo1, Whi2, Wlo2);

    // ---- layer 0
    k_gemm_mfma<8><<<gemmBlocks, 256, 0, stream>>>(x, Whi0, Wlo0, hbuf, hb16, NN);
    k_nodealpha<<<(NN * 4 + 255) / 256, 256, 0, stream>>>(hbuf, as0, ad0, asrc, adst, 4, 32);
    k_agg4m<<<waveBlocks, 256, 0, stream>>>((const uint4*)hb16, asrc, adst, row_ptr,
                                            ssrc, b0, post, gm, gdenom, 1);
    k_alpha0<<<edgeBlocks, 256, 0, stream>>>(ei, E, (const float4*)asrc, (const float4*)adst,
                                             (const float4*)gm, (const float4*)gdenom,
                                             (float4*)out_alpha);

    // ---- layer 1
    k_gemm_mfma<8><<<gemmBlocks, 256, 0, stream>>>(post, Whi1, Wlo1, hbuf, hb16, NN);
    k_nodealpha<<<(NN * 4 + 255) / 256, 256, 0, stream>>>(hbuf, as1, ad1, asrc, adst, 4, 32);
    k_agg4m<<<waveBlocks, 256, 0, stream>>>((const uint4*)hb16, asrc, adst, row_ptr,
                                            ssrc, b1, post, gm, gdenom, 0);

    // ---- layer 2 (1 head, 32 out, no concat/ELU)
    k_gemm_mfma<2><<<gemmBlocks, 256, 0, stream>>>(post, Whi2, Wlo2, hbuf, nullptr, NN);
    k_nodealpha<<<(NN + 255) / 256, 256, 0, stream>>>(hbuf, as2, ad2, asrc, adst, 1, 32);
    k_agg1m<<<waveBlocks, 256, 0, stream>>>((const float4*)hbuf, asrc, adst, row_ptr,
                                            ssrc, b2, out_final);
}

// Round 6
// 444.606 us; speedup vs baseline: 2.2282x; 1.0828x over previous
//
#include <hip/hip_runtime.h>
#include <math.h>

#define NN 50000
#define NEG 0.2f
#define TILE 4096      // edges per binning block

typedef __attribute__((ext_vector_type(8))) short short8;
typedef __attribute__((ext_vector_type(4))) float f32x4;

__device__ __forceinline__ unsigned short f2bf(float f){
    unsigned u = __float_as_uint(f);
    u += 0x7fffu + ((u >> 16) & 1u);   // round-to-nearest-even
    return (unsigned short)(u >> 16);
}
__device__ __forceinline__ float bf2f(unsigned short v){
    return __uint_as_float(((unsigned)v) << 16);
}

// exclusive scan of 256 values across a 256-thread block
__device__ __forceinline__ int excl_scan_256(int v, int* buf, int tid){
    buf[tid] = v;
    __syncthreads();
#pragma unroll
    for (int off = 1; off < 256; off <<= 1){
        int t = (tid >= off) ? buf[tid - off] : 0;
        __syncthreads();
        buf[tid] += t;
        __syncthreads();
    }
    return buf[tid] - v;
}

// ---------------------------------------------------------------- utilities
__global__ void k_zero(int* p, int n){
    int i = blockIdx.x * 256 + threadIdx.x;
    if (i < n) p[i] = 0;
}

// ---------------------- CSR build pass 1: coarse binning (bucket = dst>>8)
__global__ __launch_bounds__(256) void k_binning(const int* __restrict__ ei, int E,
        int* __restrict__ bucketCount, unsigned* __restrict__ tmp){
    __shared__ unsigned stage[TILE];
    __shared__ int hist[256], sbuf[256], exs[256], cur[256], gbase[256];
    int tid = threadIdx.x;
    int EP = E + NN;
    int tileBase = blockIdx.x * TILE;
    int cnt = min(TILE, EP - tileBase);

    hist[tid] = 0;
    __syncthreads();

    unsigned packed[16];
#pragma unroll
    for (int k = 0; k < 16; ++k){
        int e = tileBase + tid + (k << 8);
        unsigned p = 0xffffffffu;
        if (e < EP){
            int s, d;
            if (e < E){ s = ei[e]; d = ei[E + e]; } else { s = e - E; d = s; }
            p = ((unsigned)d << 16) | (unsigned)s;
            atomicAdd(&hist[d >> 8], 1);
        }
        packed[k] = p;
    }
    __syncthreads();
    int h = hist[tid];
    int ex = excl_scan_256(h, sbuf, tid);
    exs[tid] = ex;
    cur[tid] = ex;
    __syncthreads();
#pragma unroll
    for (int k = 0; k < 16; ++k){
        unsigned p = packed[k];
        if (p != 0xffffffffu){
            int b = p >> 24;
            int pos = atomicAdd(&cur[b], 1);
            stage[pos] = p;
        }
    }
    gbase[tid] = atomicAdd(&bucketCount[tid], h);
    __syncthreads();
    for (int i = tid; i < cnt; i += 256){
        unsigned p = stage[i];
        int b = p >> 24;
        tmp[(b << 14) + gbase[b] + (i - exs[b])] = p;
    }
}

// ---------------------- CSR build pass 2: per-bucket fine CSR
__global__ __launch_bounds__(256) void k_bucket_csr(int EP,
        const int* __restrict__ bucketCount, const unsigned* __restrict__ tmp,
        int* __restrict__ row_ptr, unsigned short* __restrict__ ssrc){
    __shared__ int sbuf[256], deg[256], cur[256];
    __shared__ int baseSh, nSh;
    int b = blockIdx.x;
    int tid = threadIdx.x;
    int c = bucketCount[tid];
    int exb = excl_scan_256(c, sbuf, tid);
    if (tid == b){ baseSh = exb; nSh = c; }
    deg[tid] = 0;
    __syncthreads();
    int base = baseSh, n = nSh;
    const unsigned* tb = tmp + ((size_t)b << 14);
    for (int i = tid; i < n; i += 256)
        atomicAdd(&deg[(tb[i] >> 16) & 255], 1);
    __syncthreads();
    int d = deg[tid];
    int dx = excl_scan_256(d, sbuf, tid);
    cur[tid] = dx;
    int dst = (b << 8) + tid;
    if (dst < NN) row_ptr[dst] = base + dx;
    if (b == 0 && tid == 0) row_ptr[NN] = EP;
    __syncthreads();
    for (int i = tid; i < n; i += 256){
        unsigned p = tb[i];
        int pos = atomicAdd(&cur[(p >> 16) & 255], 1);
        ssrc[base + pos] = (unsigned short)(p & 0xffffu);
    }
}

// ------------------------- pack W -> B^T bf16 hi/lo tables (one-shot, tiny)
__global__ void k_packW(const float* __restrict__ W0, const float* __restrict__ W1,
                        const float* __restrict__ W2,
                        unsigned short* __restrict__ h0, unsigned short* __restrict__ l0,
                        unsigned short* __restrict__ h1, unsigned short* __restrict__ l1,
                        unsigned short* __restrict__ h2, unsigned short* __restrict__ l2){
    int t = blockIdx.x * 256 + threadIdx.x;
    const float* W; unsigned short *ph, *pl; int Ncol; int u;
    if (t < 16384){ W = W0; ph = h0; pl = l0; Ncol = 128; u = t; }
    else if (t < 32768){ W = W1; ph = h1; pl = l1; Ncol = 128; u = t - 16384; }
    else if (t < 36864){ W = W2; ph = h2; pl = l2; Ncol = 32;  u = t - 32768; }
    else return;
    int n = u >> 7, k = u & 127;
    float f = W[k * Ncol + n];
    unsigned short hi = f2bf(f);
    unsigned short lo = f2bf(f - bf2f(hi));
    ph[n * 128 + k] = hi;
    pl[n * 128 + k] = lo;
}

// -------------------------------------- MFMA GEMM: C[M,NT*16] = A[M,128]@B
// hi/lo-compensated bf16 (3 MFMAs) ~= fp32 accuracy.
template<int NT>
__global__ __launch_bounds__(256) void k_gemm_mfma(
        const float* __restrict__ A,
        const unsigned short* __restrict__ Bhi,   // [NT*16][128] bf16 (B^T)
        const unsigned short* __restrict__ Blo,
        float* __restrict__ C, unsigned short* __restrict__ Cbf, int M){
    const int Ncol = NT * 16;
    int wave = threadIdx.x >> 6;
    int lane = threadIdx.x & 63;
    int r    = lane & 15;
    int oct  = lane >> 4;
    int rowBase = blockIdx.x * 64 + wave * 16;

    f32x4 acc[NT];
#pragma unroll
    for (int c = 0; c < NT; ++c) acc[c] = (f32x4){0.f, 0.f, 0.f, 0.f};

    int lrow = rowBase + r; if (lrow > M - 1) lrow = M - 1;
    const float* arow = A + (size_t)lrow * 128;

    for (int t = 0; t < 4; ++t){
        int k0 = t * 32 + oct * 8;
        float4 a0 = *(const float4*)&arow[k0];
        float4 a1 = *(const float4*)&arow[k0 + 4];
        float av[8] = {a0.x, a0.y, a0.z, a0.w, a1.x, a1.y, a1.z, a1.w};
        short8 ahi, alo;
#pragma unroll
        for (int j = 0; j < 8; ++j){
            unsigned short h = f2bf(av[j]);
            unsigned short l = f2bf(av[j] - bf2f(h));
            ahi[j] = (short)h; alo[j] = (short)l;
        }
#pragma unroll
        for (int c = 0; c < NT; ++c){
            short8 bhi = *(const short8*)&Bhi[(c * 16 + r) * 128 + k0];
            short8 blo = *(const short8*)&Blo[(c * 16 + r) * 128 + k0];
            acc[c] = __builtin_amdgcn_mfma_f32_16x16x32_bf16(ahi, bhi, acc[c], 0, 0, 0);
            acc[c] = __builtin_amdgcn_mfma_f32_16x16x32_bf16(alo, bhi, acc[c], 0, 0, 0);
            acc[c] = __builtin_amdgcn_mfma_f32_16x16x32_bf16(ahi, blo, acc[c], 0, 0, 0);
        }
    }
    // C/D layout: col = lane&15, row = oct*4 + reg
#pragma unroll
    for (int c = 0; c < NT; ++c){
#pragma unroll
        for (int reg = 0; reg < 4; ++reg){
            int row = rowBase + oct * 4 + reg;
            if (row < M){
                int col = c * 16 + r;
                float v = acc[c][reg];
                C[(size_t)row * Ncol + col] = v;
                if (Cbf) Cbf[(size_t)row * Ncol + col] = f2bf(v);
            }
        }
    }
}

// ------------------------------------------- per-node attention half-logits
__global__ void k_nodealpha(const float* __restrict__ h,
                            const float* __restrict__ a_s,
                            const float* __restrict__ a_d,
                            float* __restrict__ asrc, float* __restrict__ adst,
                            int H, int C){
    int t = blockIdx.x * 256 + threadIdx.x;
    if (t >= NN * H) return;
    int n = t / H, hd = t % H;
    const float* hp = h + (size_t)n * H * C + hd * C;
    float s1 = 0.f, s2 = 0.f;
    for (int c = 0; c < C; c += 4){
        float4 hv = *(const float4*)&hp[c];
        float4 av = *(const float4*)&a_s[hd * C + c];
        float4 dv = *(const float4*)&a_d[hd * C + c];
        s1 += hv.x * av.x + hv.y * av.y + hv.z * av.z + hv.w * av.w;
        s2 += hv.x * dv.x + hv.y * dv.y + hv.z * dv.z + hv.w * dv.w;
    }
    asrc[t] = s1;
    adst[t] = s2;
}

// ---------- SINGLE-PASS aggregation, 4 heads x 32 ch (bf16 h)
// No max-subtraction (logits bounded ~|13| -> exp safe in fp32): accumulate
// unnormalized sum(exp(lg)*h) and sum(exp(lg)) in ONE edge sweep, divide at
// the end. 4 edge subgroups x 16 chunk-lanes; dwordx4 bf16 gather.
__global__ __launch_bounds__(256) void k_agg4s(
        const uint4* __restrict__ hb4,            // [NN][16] dwordx4 bf16 rows
        const float* __restrict__ asrc, const float* __restrict__ adst,
        const int* __restrict__ row_ptr, const unsigned short* __restrict__ ssrc,
        const float* __restrict__ bias, float* __restrict__ outp,
        float* __restrict__ gdenom, int writeStats){
    int wave = (blockIdx.x * 256 + threadIdx.x) >> 6;
    int lane = threadIdx.x & 63;
    if (wave >= NN) return;
    int i = wave;
    int lo = row_ptr[i], hi = row_ptr[i + 1];
    int g = lane >> 4;                   // edge subgroup 0..3
    int q = lane & 15;                   // channel chunk: ch q*8..q*8+7
    int myh = q >> 2;                    // head of these channels
    float adv = adst[i * 4 + myh];

    float acc[8];
#pragma unroll
    for (int k = 0; k < 8; ++k) acc[k] = 0.f;
    float dsum = 0.f;

    int idx = lo;
#define AGG4_BODY(JJ) {                                                       \
        float lg = asrc[(JJ) * 4u + myh] + adv;                               \
        lg = fmaxf(lg, NEG * lg);                                             \
        float a = __expf(lg);                                                 \
        dsum += a;                                                            \
        uint4 gv = hb4[(JJ) * 16u + (unsigned)q];                             \
        acc[0] += a * __uint_as_float(gv.x << 16);                            \
        acc[1] += a * __uint_as_float(gv.x & 0xffff0000u);                    \
        acc[2] += a * __uint_as_float(gv.y << 16);                            \
        acc[3] += a * __uint_as_float(gv.y & 0xffff0000u);                    \
        acc[4] += a * __uint_as_float(gv.z << 16);                            \
        acc[5] += a * __uint_as_float(gv.z & 0xffff0000u);                    \
        acc[6] += a * __uint_as_float(gv.w << 16);                            \
        acc[7] += a * __uint_as_float(gv.w & 0xffff0000u); }
    for (; idx + 4 <= hi; idx += 4){
        unsigned j = ssrc[idx + g];
        AGG4_BODY(j)
    }
    if (idx + g < hi){
        unsigned j = ssrc[idx + g];
        AGG4_BODY(j)
    }
#undef AGG4_BODY
    // combine the 4 edge subgroups (lane bits 4,5), q stays fixed
#pragma unroll
    for (int k = 0; k < 8; ++k){
        acc[k] += __shfl_xor(acc[k], 16);
        acc[k] += __shfl_xor(acc[k], 32);
    }
    dsum += __shfl_xor(dsum, 16);
    dsum += __shfl_xor(dsum, 32);

    if (writeStats && g == 0 && (q & 3) == 0)
        gdenom[i * 4 + myh] = dsum;

    if (g == 0){
        float rs = 1.f / dsum;
        int c0 = q * 8;
        float4 bA = *(const float4*)&bias[c0];
        float4 bB = *(const float4*)&bias[c0 + 4];
        float o[8] = {acc[0] * rs + bA.x, acc[1] * rs + bA.y,
                      acc[2] * rs + bA.z, acc[3] * rs + bA.w,
                      acc[4] * rs + bB.x, acc[5] * rs + bB.y,
                      acc[6] * rs + bB.z, acc[7] * rs + bB.w};
#pragma unroll
        for (int k = 0; k < 8; ++k)
            o[k] = (o[k] > 0.f) ? o[k] : (__expf(o[k]) - 1.f);   // ELU
        *(float4*)&outp[(size_t)i * 128 + c0]     = make_float4(o[0], o[1], o[2], o[3]);
        *(float4*)&outp[(size_t)i * 128 + c0 + 4] = make_float4(o[4], o[5], o[6], o[7]);
    }
}

// ------------------------------------ alpha0 in ORIGINAL edge order (layer0)
// alpha = exp(lg) / gdenom[d]   (no max subtraction; gdenom unnormalized)
__global__ void k_alpha0(const int* __restrict__ ei, int E,
                         const float4* __restrict__ asrc4, const float4* __restrict__ adst4,
                         const float4* __restrict__ gd4, float4* __restrict__ out){
    int e = blockIdx.x * 256 + threadIdx.x;
    int EP = E + NN;
    if (e >= EP) return;
    int s, d;
    if (e < E){ s = ei[e]; d = ei[E + e]; } else { s = e - E; d = s; }
    float4 as = asrc4[s], ad = adst4[d], dn = gd4[d];
    float4 r;
    float lg;
    lg = as.x + ad.x; lg = fmaxf(lg, NEG * lg); r.x = __expf(lg) / dn.x;
    lg = as.y + ad.y; lg = fmaxf(lg, NEG * lg); r.y = __expf(lg) / dn.y;
    lg = as.z + ad.z; lg = fmaxf(lg, NEG * lg); r.z = __expf(lg) / dn.z;
    lg = as.w + ad.w; lg = fmaxf(lg, NEG * lg); r.w = __expf(lg) / dn.w;
    out[e] = r;
}

// ---------- SINGLE-PASS aggregation, 1 head x 32 ch (fp32 h, layer 2)
__global__ __launch_bounds__(256) void k_agg1s(
        const float4* __restrict__ h24,           // [NN][8] float4 rows
        const float* __restrict__ asrc, const float* __restrict__ adst,
        const int* __restrict__ row_ptr, const unsigned short* __restrict__ ssrc,
        const float* __restrict__ bias, float* __restrict__ outp){
    int wave = (blockIdx.x * 256 + threadIdx.x) >> 6;
    int lane = threadIdx.x & 63;
    if (wave >= NN) return;
    int i = wave;
    int lo = row_ptr[i], hi = row_ptr[i + 1];
    int g = lane >> 3;                   // edge subgroup 0..7
    int q = lane & 7;                    // channel chunk: ch q*4..q*4+3
    float adv = adst[i];

    float acc[4] = {0.f, 0.f, 0.f, 0.f};
    float dsum = 0.f;
    int idx = lo;
    for (; idx + 8 <= hi; idx += 8){
        unsigned j = ssrc[idx + g];
        float lg = asrc[j] + adv;
        lg = fmaxf(lg, NEG * lg);
        float a = __expf(lg);
        dsum += a;
        float4 v = h24[(unsigned)j * 8u + (unsigned)q];
        acc[0] += a * v.x; acc[1] += a * v.y;
        acc[2] += a * v.z; acc[3] += a * v.w;
    }
    if (idx + g < hi){
        unsigned j = ssrc[idx + g];
        float lg = asrc[j] + adv;
        lg = fmaxf(lg, NEG * lg);
        float a = __expf(lg);
        dsum += a;
        float4 v = h24[(unsigned)j * 8u + (unsigned)q];
        acc[0] += a * v.x; acc[1] += a * v.y;
        acc[2] += a * v.z; acc[3] += a * v.w;
    }
#pragma unroll
    for (int k = 0; k < 4; ++k){
        acc[k] += __shfl_xor(acc[k], 8);
        acc[k] += __shfl_xor(acc[k], 16);
        acc[k] += __shfl_xor(acc[k], 32);
    }
    dsum += __shfl_xor(dsum, 8);
    dsum += __shfl_xor(dsum, 16);
    dsum += __shfl_xor(dsum, 32);
    if (g == 0){
        float rs = 1.f / dsum;
        float4 b = *(const float4*)&bias[q * 4];
        *(float4*)&outp[(size_t)i * 32 + q * 4] =
            make_float4(acc[0] * rs + b.x, acc[1] * rs + b.y,
                        acc[2] * rs + b.z, acc[3] * rs + b.w);
    }
}

// ---------------------------------------------------------------- launcher
extern "C" void kernel_launch(void* const* d_in, const int* in_sizes, int n_in,
                              void* d_out, int out_size, void* d_ws, size_t ws_size,
                              hipStream_t stream){
    const float* x   = (const float*)d_in[0];
    const int*   ei  = (const int*)  d_in[1];
    const float* W0  = (const float*)d_in[2];
    const float* as0 = (const float*)d_in[3];
    const float* ad0 = (const float*)d_in[4];
    const float* b0  = (const float*)d_in[5];
    const float* W1  = (const float*)d_in[6];
    const float* as1 = (const float*)d_in[7];
    const float* ad1 = (const float*)d_in[8];
    const float* b1  = (const float*)d_in[9];
    const float* W2  = (const float*)d_in[10];
    const float* as2 = (const float*)d_in[11];
    const float* ad2 = (const float*)d_in[12];
    const float* b2  = (const float*)d_in[13];

    const int E  = in_sizes[1] / 2;
    const int EP = E + NN;

    char* w = (char*)d_ws;
    size_t off = 0;
    auto carve = [&](size_t bytes) -> char* {
        char* p = w + off;
        off += (bytes + 255) & ~(size_t)255;
        return p;
    };
    int*            bucketCount = (int*)       carve(sizeof(int) * 256);
    int*            row_ptr = (int*)           carve(sizeof(int) * (NN + 1));
    unsigned short* ssrc    = (unsigned short*)carve(sizeof(short) * (size_t)EP);
    float*          hbuf    = (float*)         carve(sizeof(float) * (size_t)NN * 128);
    unsigned short* hb16    = (unsigned short*)carve(sizeof(short) * (size_t)NN * 128);
    float*          post    = (float*)         carve(sizeof(float) * (size_t)NN * 128);
    float*          asrc    = (float*)         carve(sizeof(float) * NN * 4);
    float*          adst    = (float*)         carve(sizeof(float) * NN * 4);
    float*          gdenom  = (float*)         carve(sizeof(float) * NN * 4);
    unsigned short* Whi0    = (unsigned short*)carve(sizeof(short) * 16384);
    unsigned short* Wlo0    = (unsigned short*)carve(sizeof(short) * 16384);
    unsigned short* Whi1    = (unsigned short*)carve(sizeof(short) * 16384);
    unsigned short* Wlo1    = (unsigned short*)carve(sizeof(short) * 16384);
    unsigned short* Whi2    = (unsigned short*)carve(sizeof(short) * 4096);
    unsigned short* Wlo2    = (unsigned short*)carve(sizeof(short) * 4096);
    // tmp (16MB) aliases post (25.6MB): consumed by k_bucket_csr before
    // layer-0 agg4s first writes post (stream-ordered).
    unsigned*       tmp     = (unsigned*)post;

    float* out_alpha = (float*)d_out;                  // [EP, 4]
    float* out_final = (float*)d_out + (size_t)EP * 4; // [NN, 32]

    const int edgeBlocks = (EP + 255) / 256;
    const int waveBlocks = (NN + 3) / 4;
    const int gemmBlocks = (NN + 63) / 64;

    // ---- CSR build + weight pack
    k_zero      <<<1, 256, 0, stream>>>(bucketCount, 256);
    k_binning   <<<(EP + TILE - 1) / TILE, 256, 0, stream>>>(ei, E, bucketCount, tmp);
    k_bucket_csr<<<256, 256, 0, stream>>>(EP, bucketCount, tmp, row_ptr, ssrc);
    k_packW     <<<144, 256, 0, stream>>>(W0, W1, W2, Whi0, Wlo0, Whi1, Wlo1, Whi2, Wlo2);

    // ---- layer 0
    k_gemm_mfma<8><<<gemmBlocks, 256, 0, stream>>>(x, Whi0, Wlo0, hbuf, hb16, NN);
    k_nodealpha<<<(NN * 4 + 255) / 256, 256, 0, stream>>>(hbuf, as0, ad0, asrc, adst, 4, 32);
    k_agg4s<<<waveBlocks, 256, 0, stream>>>((const uint4*)hb16, asrc, adst, row_ptr,
                                            ssrc, b0, post, gdenom, 1);
    k_alpha0<<<edgeBlocks, 256, 0, stream>>>(ei, E, (const float4*)asrc, (const float4*)adst,
                                             (const float4*)gdenom, (float4*)out_alpha);

    // ---- layer 1
    k_gemm_mfma<8><<<gemmBlocks, 256, 0, stream>>>(post, Whi1, Wlo1, hbuf, hb16, NN);
    k_nodealpha<<<(NN * 4 + 255) / 256, 256, 0, stream>>>(hbuf, as1, ad1, asrc, adst, 4, 32);
    k_agg4s<<<waveBlocks, 256, 0, stream>>>((const uint4*)hb16, asrc, adst, row_ptr,
                                            ssrc, b1, post, gdenom, 0);

    // ---- layer 2 (1 head, 32 out, no concat/ELU)
    k_gemm_mfma<2><<<gemmBlocks, 256, 0, stream>>>(post, Whi2, Wlo2, hbuf, nullptr, NN);
    k_nodealpha<<<(NN + 255) / 256, 256, 0, stream>>>(hbuf, as2, ad2, asrc, adst, 1, 32);
    k_agg1s<<<waveBlocks, 256, 0, stream>>>((const float4*)hbuf, asrc, adst, row_ptr,
                                            ssrc, b2, out_final);
}

// Round 7
// 435.788 us; speedup vs baseline: 2.2733x; 1.0202x over previous
//
#include <hip/hip_runtime.h>
#include <math.h>

#define NN 50000
#define NEG 0.2f
#define TILE 4096      // edges per binning block

typedef __attribute__((ext_vector_type(8))) short short8;
typedef __attribute__((ext_vector_type(4))) float f32x4;

__device__ __forceinline__ unsigned short f2bf(float f){
    unsigned u = __float_as_uint(f);
    u += 0x7fffu + ((u >> 16) & 1u);   // round-to-nearest-even
    return (unsigned short)(u >> 16);
}
__device__ __forceinline__ float bf2f(unsigned short v){
    return __uint_as_float(((unsigned)v) << 16);
}

// exclusive scan of 256 values across a 256-thread block
__device__ __forceinline__ int excl_scan_256(int v, int* buf, int tid){
    buf[tid] = v;
    __syncthreads();
#pragma unroll
    for (int off = 1; off < 256; off <<= 1){
        int t = (tid >= off) ? buf[tid - off] : 0;
        __syncthreads();
        buf[tid] += t;
        __syncthreads();
    }
    return buf[tid] - v;
}

// ---------------------- CSR build pass 1: coarse binning (bucket = dst>>8)
__global__ __launch_bounds__(256) void k_binning(const int* __restrict__ ei, int E,
        int* __restrict__ bucketCount, unsigned* __restrict__ tmp){
    __shared__ unsigned stage[TILE];
    __shared__ int hist[256], sbuf[256], exs[256], cur[256], gbase[256];
    int tid = threadIdx.x;
    int EP = E + NN;
    int tileBase = blockIdx.x * TILE;
    int cnt = min(TILE, EP - tileBase);

    hist[tid] = 0;
    __syncthreads();

    unsigned packed[16];
#pragma unroll
    for (int k = 0; k < 16; ++k){
        int e = tileBase + tid + (k << 8);
        unsigned p = 0xffffffffu;
        if (e < EP){
            int s, d;
            if (e < E){ s = ei[e]; d = ei[E + e]; } else { s = e - E; d = s; }
            p = ((unsigned)d << 16) | (unsigned)s;
            atomicAdd(&hist[d >> 8], 1);
        }
        packed[k] = p;
    }
    __syncthreads();
    int h = hist[tid];
    int ex = excl_scan_256(h, sbuf, tid);
    exs[tid] = ex;
    cur[tid] = ex;
    __syncthreads();
#pragma unroll
    for (int k = 0; k < 16; ++k){
        unsigned p = packed[k];
        if (p != 0xffffffffu){
            int b = p >> 24;
            int pos = atomicAdd(&cur[b], 1);
            stage[pos] = p;
        }
    }
    gbase[tid] = atomicAdd(&bucketCount[tid], h);
    __syncthreads();
    for (int i = tid; i < cnt; i += 256){
        unsigned p = stage[i];
        int b = p >> 24;
        tmp[(b << 14) + gbase[b] + (i - exs[b])] = p;
    }
}

// ---------------------- CSR build pass 2: per-bucket fine CSR
__global__ __launch_bounds__(256) void k_bucket_csr(int EP,
        const int* __restrict__ bucketCount, const unsigned* __restrict__ tmp,
        int* __restrict__ row_ptr, unsigned short* __restrict__ ssrc){
    __shared__ int sbuf[256], deg[256], cur[256];
    __shared__ int baseSh, nSh;
    int b = blockIdx.x;
    int tid = threadIdx.x;
    int c = bucketCount[tid];
    int exb = excl_scan_256(c, sbuf, tid);
    if (tid == b){ baseSh = exb; nSh = c; }
    deg[tid] = 0;
    __syncthreads();
    int base = baseSh, n = nSh;
    const unsigned* tb = tmp + ((size_t)b << 14);
    for (int i = tid; i < n; i += 256)
        atomicAdd(&deg[(tb[i] >> 16) & 255], 1);
    __syncthreads();
    int d = deg[tid];
    int dx = excl_scan_256(d, sbuf, tid);
    cur[tid] = dx;
    int dst = (b << 8) + tid;
    if (dst < NN) row_ptr[dst] = base + dx;
    if (b == 0 && tid == 0) row_ptr[NN] = EP;
    __syncthreads();
    for (int i = tid; i < n; i += 256){
        unsigned p = tb[i];
        int pos = atomicAdd(&cur[(p >> 16) & 255], 1);
        ssrc[base + pos] = (unsigned short)(p & 0xffffu);
    }
}

// ------------------------- pack W -> B^T bf16 hi/lo tables (one-shot, tiny)
__global__ void k_packW(const float* __restrict__ W0, const float* __restrict__ W1,
                        const float* __restrict__ W2,
                        unsigned short* __restrict__ h0, unsigned short* __restrict__ l0,
                        unsigned short* __restrict__ h1, unsigned short* __restrict__ l1,
                        unsigned short* __restrict__ h2, unsigned short* __restrict__ l2){
    int t = blockIdx.x * 256 + threadIdx.x;
    const float* W; unsigned short *ph, *pl; int Ncol; int u;
    if (t < 16384){ W = W0; ph = h0; pl = l0; Ncol = 128; u = t; }
    else if (t < 32768){ W = W1; ph = h1; pl = l1; Ncol = 128; u = t - 16384; }
    else if (t < 36864){ W = W2; ph = h2; pl = l2; Ncol = 32;  u = t - 32768; }
    else return;
    int n = u >> 7, k = u & 127;
    float f = W[k * Ncol + n];
    unsigned short hi = f2bf(f);
    unsigned short lo = f2bf(f - bf2f(hi));
    ph[n * 128 + k] = hi;
    pl[n * 128 + k] = lo;
}

// -------------------------------------- MFMA GEMM: C[M,NT*16] = A[M,128]@B
// hi/lo-compensated bf16 (3 MFMAs) ~= fp32 accuracy.
template<int NT>
__global__ __launch_bounds__(256) void k_gemm_mfma(
        const float* __restrict__ A,
        const unsigned short* __restrict__ Bhi,   // [NT*16][128] bf16 (B^T)
        const unsigned short* __restrict__ Blo,
        float* __restrict__ C, unsigned short* __restrict__ Cbf, int M){
    const int Ncol = NT * 16;
    int wave = threadIdx.x >> 6;
    int lane = threadIdx.x & 63;
    int r    = lane & 15;
    int oct  = lane >> 4;
    int rowBase = blockIdx.x * 64 + wave * 16;

    f32x4 acc[NT];
#pragma unroll
    for (int c = 0; c < NT; ++c) acc[c] = (f32x4){0.f, 0.f, 0.f, 0.f};

    int lrow = rowBase + r; if (lrow > M - 1) lrow = M - 1;
    const float* arow = A + (size_t)lrow * 128;

    for (int t = 0; t < 4; ++t){
        int k0 = t * 32 + oct * 8;
        float4 a0 = *(const float4*)&arow[k0];
        float4 a1 = *(const float4*)&arow[k0 + 4];
        float av[8] = {a0.x, a0.y, a0.z, a0.w, a1.x, a1.y, a1.z, a1.w};
        short8 ahi, alo;
#pragma unroll
        for (int j = 0; j < 8; ++j){
            unsigned short h = f2bf(av[j]);
            unsigned short l = f2bf(av[j] - bf2f(h));
            ahi[j] = (short)h; alo[j] = (short)l;
        }
#pragma unroll
        for (int c = 0; c < NT; ++c){
            short8 bhi = *(const short8*)&Bhi[(c * 16 + r) * 128 + k0];
            short8 blo = *(const short8*)&Blo[(c * 16 + r) * 128 + k0];
            acc[c] = __builtin_amdgcn_mfma_f32_16x16x32_bf16(ahi, bhi, acc[c], 0, 0, 0);
            acc[c] = __builtin_amdgcn_mfma_f32_16x16x32_bf16(alo, bhi, acc[c], 0, 0, 0);
            acc[c] = __builtin_amdgcn_mfma_f32_16x16x32_bf16(ahi, blo, acc[c], 0, 0, 0);
        }
    }
    // C/D layout: col = lane&15, row = oct*4 + reg
#pragma unroll
    for (int c = 0; c < NT; ++c){
#pragma unroll
        for (int reg = 0; reg < 4; ++reg){
            int row = rowBase + oct * 4 + reg;
            if (row < M){
                int col = c * 16 + r;
                float v = acc[c][reg];
                C[(size_t)row * Ncol + col] = v;
                if (Cbf) Cbf[(size_t)row * Ncol + col] = f2bf(v);
            }
        }
    }
}

// ------------------------------------------- per-node attention half-logits
__global__ void k_nodealpha(const float* __restrict__ h,
                            const float* __restrict__ a_s,
                            const float* __restrict__ a_d,
                            float* __restrict__ asrc, float* __restrict__ adst,
                            int H, int C){
    int t = blockIdx.x * 256 + threadIdx.x;
    if (t >= NN * H) return;
    int n = t / H, hd = t % H;
    const float* hp = h + (size_t)n * H * C + hd * C;
    float s1 = 0.f, s2 = 0.f;
    for (int c = 0; c < C; c += 4){
        float4 hv = *(const float4*)&hp[c];
        float4 av = *(const float4*)&a_s[hd * C + c];
        float4 dv = *(const float4*)&a_d[hd * C + c];
        s1 += hv.x * av.x + hv.y * av.y + hv.z * av.z + hv.w * av.w;
        s2 += hv.x * dv.x + hv.y * dv.y + hv.z * dv.z + hv.w * dv.w;
    }
    asrc[t] = s1;
    adst[t] = s2;
}

// ---------- SINGLE-PASS aggregation, 4 heads x 32 ch (bf16 h)
// Unnormalized sum(exp(lg)*h), sum(exp(lg)); one edge sweep.
// 4 edge subgroups x 16 chunk-lanes; each subgroup takes an ADJACENT PAIR of
// edges per iter (8 edges/wave-iter): one dword ssrc read, both h-row loads
// in flight together (2x MLP vs round 6).
__global__ __launch_bounds__(256) void k_agg4s(
        const uint4* __restrict__ hb4,            // [NN][16] dwordx4 bf16 rows
        const float* __restrict__ asrc, const float* __restrict__ adst,
        const int* __restrict__ row_ptr, const unsigned short* __restrict__ ssrc,
        const float* __restrict__ bias, float* __restrict__ outp,
        float* __restrict__ gdenom, int writeStats){
    int wave = (blockIdx.x * 256 + threadIdx.x) >> 6;
    int lane = threadIdx.x & 63;
    if (wave >= NN) return;
    int i = wave;
    int lo = row_ptr[i], hi = row_ptr[i + 1];
    int g = lane >> 4;                   // edge subgroup 0..3
    int q = lane & 15;                   // channel chunk: ch q*8..q*8+7
    int myh = q >> 2;                    // head of these channels
    float adv = adst[i * 4 + myh];

    float acc[8];
#pragma unroll
    for (int k = 0; k < 8; ++k) acc[k] = 0.f;
    float dsum = 0.f;

#define AGG4_FMA(AA, GV) {                                                    \
        acc[0] += (AA) * __uint_as_float((GV).x << 16);                       \
        acc[1] += (AA) * __uint_as_float((GV).x & 0xffff0000u);               \
        acc[2] += (AA) * __uint_as_float((GV).y << 16);                       \
        acc[3] += (AA) * __uint_as_float((GV).y & 0xffff0000u);               \
        acc[4] += (AA) * __uint_as_float((GV).z << 16);                       \
        acc[5] += (AA) * __uint_as_float((GV).z & 0xffff0000u);               \
        acc[6] += (AA) * __uint_as_float((GV).w << 16);                       \
        acc[7] += (AA) * __uint_as_float((GV).w & 0xffff0000u); }
#define AGG4_ONE(JJ) {                                                        \
        float lg_ = asrc[(JJ) * 4u + myh] + adv;                              \
        lg_ = fmaxf(lg_, NEG * lg_);                                          \
        float a_ = __expf(lg_);                                               \
        dsum += a_;                                                           \
        uint4 gv_ = hb4[(JJ) * 16u + (unsigned)q];                            \
        AGG4_FMA(a_, gv_) }

    int idx = lo;
    if (lo & 1){                         // peel to even alignment
        if (g == 0){ unsigned j = ssrc[lo]; AGG4_ONE(j) }
        idx = lo + 1;
    }
    for (; idx + 8 <= hi; idx += 8){
        unsigned pair = *(const unsigned*)&ssrc[idx + 2 * g];   // aligned: idx even
        unsigned j0 = pair & 0xffffu, j1 = pair >> 16;
        float s0 = asrc[j0 * 4u + myh];
        float s1 = asrc[j1 * 4u + myh];
        uint4 gv0 = hb4[j0 * 16u + (unsigned)q];
        uint4 gv1 = hb4[j1 * 16u + (unsigned)q];
        float lg0 = s0 + adv; lg0 = fmaxf(lg0, NEG * lg0);
        float lg1 = s1 + adv; lg1 = fmaxf(lg1, NEG * lg1);
        float a0 = __expf(lg0), a1 = __expf(lg1);
        dsum += a0 + a1;
        AGG4_FMA(a0, gv0)
        AGG4_FMA(a1, gv1)
    }
    {   // remainder < 8 edges
        int k0 = idx + 2 * g, k1 = k0 + 1;
        if (k0 < hi){ unsigned j = ssrc[k0]; AGG4_ONE(j) }
        if (k1 < hi){ unsigned j = ssrc[k1]; AGG4_ONE(j) }
    }
#undef AGG4_ONE
#undef AGG4_FMA
    // combine the 4 edge subgroups (lane bits 4,5), q stays fixed
#pragma unroll
    for (int k = 0; k < 8; ++k){
        acc[k] += __shfl_xor(acc[k], 16);
        acc[k] += __shfl_xor(acc[k], 32);
    }
    dsum += __shfl_xor(dsum, 16);
    dsum += __shfl_xor(dsum, 32);

    if (writeStats && g == 0 && (q & 3) == 0)
        gdenom[i * 4 + myh] = dsum;

    if (g == 0){
        float rs = 1.f / dsum;
        int c0 = q * 8;
        float4 bA = *(const float4*)&bias[c0];
        float4 bB = *(const float4*)&bias[c0 + 4];
        float o[8] = {acc[0] * rs + bA.x, acc[1] * rs + bA.y,
                      acc[2] * rs + bA.z, acc[3] * rs + bA.w,
                      acc[4] * rs + bB.x, acc[5] * rs + bB.y,
                      acc[6] * rs + bB.z, acc[7] * rs + bB.w};
#pragma unroll
        for (int k = 0; k < 8; ++k)
            o[k] = (o[k] > 0.f) ? o[k] : (__expf(o[k]) - 1.f);   // ELU
        *(float4*)&outp[(size_t)i * 128 + c0]     = make_float4(o[0], o[1], o[2], o[3]);
        *(float4*)&outp[(size_t)i * 128 + c0 + 4] = make_float4(o[4], o[5], o[6], o[7]);
    }
}

// ------------------------------------ alpha0 in ORIGINAL edge order (layer0)
__global__ void k_alpha0(const int* __restrict__ ei, int E,
                         const float4* __restrict__ asrc4, const float4* __restrict__ adst4,
                         const float4* __restrict__ gd4, float4* __restrict__ out){
    int e = blockIdx.x * 256 + threadIdx.x;
    int EP = E + NN;
    if (e >= EP) return;
    int s, d;
    if (e < E){ s = ei[e]; d = ei[E + e]; } else { s = e - E; d = s; }
    float4 as = asrc4[s], ad = adst4[d], dn = gd4[d];
    float4 r;
    float lg;
    lg = as.x + ad.x; lg = fmaxf(lg, NEG * lg); r.x = __expf(lg) / dn.x;
    lg = as.y + ad.y; lg = fmaxf(lg, NEG * lg); r.y = __expf(lg) / dn.y;
    lg = as.z + ad.z; lg = fmaxf(lg, NEG * lg); r.z = __expf(lg) / dn.z;
    lg = as.w + ad.w; lg = fmaxf(lg, NEG * lg); r.w = __expf(lg) / dn.w;
    out[e] = r;
}

// ---------- SINGLE-PASS aggregation, 1 head x 32 ch (fp32 h, layer 2)
// 8 subgroups x 8 chunk-lanes; adjacent-pair edges (16 edges/wave-iter).
__global__ __launch_bounds__(256) void k_agg1s(
        const float4* __restrict__ h24,           // [NN][8] float4 rows
        const float* __restrict__ asrc, const float* __restrict__ adst,
        const int* __restrict__ row_ptr, const unsigned short* __restrict__ ssrc,
        const float* __restrict__ bias, float* __restrict__ outp){
    int wave = (blockIdx.x * 256 + threadIdx.x) >> 6;
    int lane = threadIdx.x & 63;
    if (wave >= NN) return;
    int i = wave;
    int lo = row_ptr[i], hi = row_ptr[i + 1];
    int g = lane >> 3;                   // edge subgroup 0..7
    int q = lane & 7;                    // channel chunk: ch q*4..q*4+3
    float adv = adst[i];

    float acc[4] = {0.f, 0.f, 0.f, 0.f};
    float dsum = 0.f;

#define AGG1_ONE(JJ) {                                                        \
        float lg_ = asrc[(JJ)] + adv;                                         \
        lg_ = fmaxf(lg_, NEG * lg_);                                          \
        float a_ = __expf(lg_);                                               \
        dsum += a_;                                                           \
        float4 v_ = h24[(JJ) * 8u + (unsigned)q];                             \
        acc[0] += a_ * v_.x; acc[1] += a_ * v_.y;                             \
        acc[2] += a_ * v_.z; acc[3] += a_ * v_.w; }

    int idx = lo;
    if (lo & 1){
        if (g == 0){ unsigned j = ssrc[lo]; AGG1_ONE(j) }
        idx = lo + 1;
    }
    for (; idx + 16 <= hi; idx += 16){
        unsigned pair = *(const unsigned*)&ssrc[idx + 2 * g];
        unsigned j0 = pair & 0xffffu, j1 = pair >> 16;
        float s0 = asrc[j0];
        float s1 = asrc[j1];
        float4 v0 = h24[j0 * 8u + (unsigned)q];
        float4 v1 = h24[j1 * 8u + (unsigned)q];
        float lg0 = s0 + adv; lg0 = fmaxf(lg0, NEG * lg0);
        float lg1 = s1 + adv; lg1 = fmaxf(lg1, NEG * lg1);
        float a0 = __expf(lg0), a1 = __expf(lg1);
        dsum += a0 + a1;
        acc[0] += a0 * v0.x; acc[1] += a0 * v0.y;
        acc[2] += a0 * v0.z; acc[3] += a0 * v0.w;
        acc[0] += a1 * v1.x; acc[1] += a1 * v1.y;
        acc[2] += a1 * v1.z; acc[3] += a1 * v1.w;
    }
    {   // remainder < 16 edges
        int k0 = idx + 2 * g, k1 = k0 + 1;
        if (k0 < hi){ unsigned j = ssrc[k0]; AGG1_ONE(j) }
        if (k1 < hi){ unsigned j = ssrc[k1]; AGG1_ONE(j) }
    }
#undef AGG1_ONE
#pragma unroll
    for (int k = 0; k < 4; ++k){
        acc[k] += __shfl_xor(acc[k], 8);
        acc[k] += __shfl_xor(acc[k], 16);
        acc[k] += __shfl_xor(acc[k], 32);
    }
    dsum += __shfl_xor(dsum, 8);
    dsum += __shfl_xor(dsum, 16);
    dsum += __shfl_xor(dsum, 32);
    if (g == 0){
        float rs = 1.f / dsum;
        float4 b = *(const float4*)&bias[q * 4];
        *(float4*)&outp[(size_t)i * 32 + q * 4] =
            make_float4(acc[0] * rs + b.x, acc[1] * rs + b.y,
                        acc[2] * rs + b.z, acc[3] * rs + b.w);
    }
}

// ---------------------------------------------------------------- launcher
extern "C" void kernel_launch(void* const* d_in, const int* in_sizes, int n_in,
                              void* d_out, int out_size, void* d_ws, size_t ws_size,
                              hipStream_t stream){
    const float* x   = (const float*)d_in[0];
    const int*   ei  = (const int*)  d_in[1];
    const float* W0  = (const float*)d_in[2];
    const float* as0 = (const float*)d_in[3];
    const float* ad0 = (const float*)d_in[4];
    const float* b0  = (const float*)d_in[5];
    const float* W1  = (const float*)d_in[6];
    const float* as1 = (const float*)d_in[7];
    const float* ad1 = (const float*)d_in[8];
    const float* b1  = (const float*)d_in[9];
    const float* W2  = (const float*)d_in[10];
    const float* as2 = (const float*)d_in[11];
    const float* ad2 = (const float*)d_in[12];
    const float* b2  = (const float*)d_in[13];

    const int E  = in_sizes[1] / 2;
    const int EP = E + NN;

    char* w = (char*)d_ws;
    size_t off = 0;
    auto carve = [&](size_t bytes) -> char* {
        char* p = w + off;
        off += (bytes + 255) & ~(size_t)255;
        return p;
    };
    int*            bucketCount = (int*)       carve(sizeof(int) * 256);
    int*            row_ptr = (int*)           carve(sizeof(int) * (NN + 1));
    unsigned short* ssrc    = (unsigned short*)carve(sizeof(short) * ((size_t)EP + 2));
    float*          hbuf    = (float*)         carve(sizeof(float) * (size_t)NN * 128);
    unsigned short* hb16    = (unsigned short*)carve(sizeof(short) * (size_t)NN * 128);
    float*          post    = (float*)         carve(sizeof(float) * (size_t)NN * 128);
    float*          asrc    = (float*)         carve(sizeof(float) * NN * 4);
    float*          adst    = (float*)         carve(sizeof(float) * NN * 4);
    float*          gdenom  = (float*)         carve(sizeof(float) * NN * 4);
    unsigned short* Whi0    = (unsigned short*)carve(sizeof(short) * 16384);
    unsigned short* Wlo0    = (unsigned short*)carve(sizeof(short) * 16384);
    unsigned short* Whi1    = (unsigned short*)carve(sizeof(short) * 16384);
    unsigned short* Wlo1    = (unsigned short*)carve(sizeof(short) * 16384);
    unsigned short* Whi2    = (unsigned short*)carve(sizeof(short) * 4096);
    unsigned short* Wlo2    = (unsigned short*)carve(sizeof(short) * 4096);
    // tmp (16MB) aliases post (25.6MB): consumed by k_bucket_csr before
    // layer-0 agg4s first writes post (stream-ordered).
    unsigned*       tmp     = (unsigned*)post;

    float* out_alpha = (float*)d_out;                  // [EP, 4]
    float* out_final = (float*)d_out + (size_t)EP * 4; // [NN, 32]

    const int edgeBlocks = (EP + 255) / 256;
    const int waveBlocks = (NN + 3) / 4;
    const int gemmBlocks = (NN + 63) / 64;

    // ---- CSR build + weight pack
    hipMemsetAsync(bucketCount, 0, sizeof(int) * 256, stream);
    k_binning   <<<(EP + TILE - 1) / TILE, 256, 0, stream>>>(ei, E, bucketCount, tmp);
    k_bucket_csr<<<256, 256, 0, stream>>>(EP, bucketCount, tmp, row_ptr, ssrc);
    k_packW     <<<144, 256, 0, stream>>>(W0, W1, W2, Whi0, Wlo0, Whi1, Wlo1, Whi2, Wlo2);

    // ---- layer 0
    k_gemm_mfma<8><<<gemmBlocks, 256, 0, stream>>>(x, Whi0, Wlo0, hbuf, hb16, NN);
    k_nodealpha<<<(NN * 4 + 255) / 256, 256, 0, stream>>>(hbuf, as0, ad0, asrc, adst, 4, 32);
    k_agg4s<<<waveBlocks, 256, 0, stream>>>((const uint4*)hb16, asrc, adst, row_ptr,
                                            ssrc, b0, post, gdenom, 1);
    k_alpha0<<<edgeBlocks, 256, 0, stream>>>(ei, E, (const float4*)asrc, (const float4*)adst,
                                             (const float4*)gdenom, (float4*)out_alpha);

    // ---- layer 1
    k_gemm_mfma<8><<<gemmBlocks, 256, 0, stream>>>(post, Whi1, Wlo1, hbuf, hb16, NN);
    k_nodealpha<<<(NN * 4 + 255) / 256, 256, 0, stream>>>(hbuf, as1, ad1, asrc, adst, 4, 32);
    k_agg4s<<<waveBlocks, 256, 0, stream>>>((const uint4*)hb16, asrc, adst, row_ptr,
                                            ssrc, b1, post, gdenom, 0);

    // ---- layer 2 (1 head, 32 out, no concat/ELU)
    k_gemm_mfma<2><<<gemmBlocks, 256, 0, stream>>>(post, Whi2, Wlo2, hbuf, nullptr, NN);
    k_nodealpha<<<(NN + 255) / 256, 256, 0, stream>>>(hbuf, as2, ad2, asrc, adst, 1, 32);
    k_agg1s<<<waveBlocks, 256, 0, stream>>>((const float4*)hbuf, asrc, adst, row_ptr,
                                            ssrc, b2, out_final);
}